// Round 1
// baseline (979.175 us; speedup 1.0000x reference)
//
#include <hip/hip_runtime.h>
#include <math.h>

#define NN 50000

__device__ inline float wred_max(float v){
  #pragma unroll
  for(int s=32;s>0;s>>=1) v=fmaxf(v,__shfl_xor(v,s,64));
  return v;
}
__device__ inline float wred_sum(float v){
  #pragma unroll
  for(int s=32;s>0;s>>=1) v+=__shfl_xor(v,s,64);
  return v;
}
__device__ inline float lrelu(float x){ return x>0.f? x : 0.2f*x; }

// ---------------- CSR build ----------------
__global__ void hist_k(const int* __restrict__ dstA,int* __restrict__ counts,int E){
  int i=blockIdx.x*blockDim.x+threadIdx.x;
  if(i<E) atomicAdd(&counts[dstA[i]],1);
}

__global__ void scan_k(const int* __restrict__ counts,int* __restrict__ offs,int N,int E){
  __shared__ int sd[1024];
  __shared__ int srun;
  int t=threadIdx.x;
  if(t==0) srun=0;
  __syncthreads();
  for(int base=0;base<N;base+=1024){
    int v=(base+t<N)?counts[base+t]:0;
    sd[t]=v;
    __syncthreads();
    for(int s=1;s<1024;s<<=1){
      int a=(t>=s)?sd[t-s]:0;
      __syncthreads();
      sd[t]+=a;
      __syncthreads();
    }
    int run=srun;
    if(base+t<N) offs[base+t]=run+sd[t]-v;  // exclusive prefix
    __syncthreads();
    if(t==1023) srun=run+sd[1023];
    __syncthreads();
  }
  if(t==0) offs[N]=E;
}

__global__ void scatter_k(const int* __restrict__ srcA,const int* __restrict__ dstA,
                          const int* __restrict__ offs,int* cur,int* __restrict__ ssrc,int E){
  int i=blockIdx.x*blockDim.x+threadIdx.x;
  if(i<E){ int d=dstA[i]; int p=offs[d]+atomicAdd(&cur[d],1); ssrc[p]=srcA[i]; }
}

// ---------------- f32 tiled GEMM: C[M,N] = A[M,K] @ B[K,N] ----------------
__global__ __launch_bounds__(256) void gemm_k(const float* __restrict__ A,const float* __restrict__ B,
                                              float* __restrict__ C,int M,int N,int K){
  __shared__ float sA[16][65];
  __shared__ float sB[16][65];
  int tx=threadIdx.x&15, ty=threadIdx.x>>4;
  int bm=blockIdx.y*64, bn=blockIdx.x*64;
  float acc[4][4]={};
  for(int k0=0;k0<K;k0+=16){
    for(int i=threadIdx.x;i<64*16;i+=256){
      int r=i>>4,c=i&15;
      int gr=bm+r;
      sA[c][r]=(gr<M)?A[(size_t)gr*K+k0+c]:0.f;
    }
    for(int i=threadIdx.x;i<16*64;i+=256){
      int r=i>>6,c=i&63;
      int gc=bn+c;
      sB[r][c]=(gc<N)?B[(size_t)(k0+r)*N+gc]:0.f;
    }
    __syncthreads();
    #pragma unroll
    for(int kk=0;kk<16;kk++){
      float a[4],b[4];
      #pragma unroll
      for(int i=0;i<4;i++) a[i]=sA[kk][ty*4+i];
      #pragma unroll
      for(int j=0;j<4;j++) b[j]=sB[kk][tx*4+j];
      #pragma unroll
      for(int i=0;i<4;i++)
        #pragma unroll
        for(int j=0;j<4;j++) acc[i][j]+=a[i]*b[j];
    }
    __syncthreads();
  }
  #pragma unroll
  for(int i=0;i<4;i++){
    int gr=bm+ty*4+i;
    if(gr<M){
      #pragma unroll
      for(int j=0;j<4;j++){
        int gc=bn+tx*4+j;
        if(gc<N) C[(size_t)gr*N+gc]=acc[i][j];
      }
    }
  }
}

// ---------------- attention dot products ----------------
// heads=4, ch=64: asrc[n,h] = sum_c h[n,h*64+c]*aS[h*64+c]
__global__ __launch_bounds__(256) void attdot4_k(const float* __restrict__ h,
    const float* __restrict__ aS,const float* __restrict__ aD,
    float* __restrict__ as_,float* __restrict__ ad_,int N){
  int lane=threadIdx.x&63, wv=threadIdx.x>>6;
  int n=blockIdx.x*4+wv;
  if(n>=N) return;
  const float* hn=h+(size_t)n*256;
  float ps[4],pd[4];
  #pragma unroll
  for(int k=0;k<4;k++){ float v=hn[k*64+lane]; ps[k]=v*aS[k*64+lane]; pd[k]=v*aD[k*64+lane]; }
  #pragma unroll
  for(int k=0;k<4;k++){ ps[k]=wred_sum(ps[k]); pd[k]=wred_sum(pd[k]); }
  if(lane==0){
    #pragma unroll
    for(int k=0;k<4;k++){ as_[n*4+k]=ps[k]; ad_[n*4+k]=pd[k]; }
  }
}

// heads=1, ch=32
__global__ __launch_bounds__(256) void attdot1_k(const float* __restrict__ h,
    const float* __restrict__ aS,const float* __restrict__ aD,
    float* __restrict__ as_,float* __restrict__ ad_,int N){
  int lane=threadIdx.x&63, wv=threadIdx.x>>6;
  int n=blockIdx.x*4+wv; if(n>=N) return;
  float v=(lane<32)?h[(size_t)n*32+lane]:0.f;
  float ps=(lane<32)?v*aS[lane]:0.f;
  float pd=(lane<32)?v*aD[lane]:0.f;
  ps=wred_sum(ps); pd=wred_sum(pd);
  if(lane==0){ as_[n]=ps; ad_[n]=pd; }
}

// ---------------- aggregation (heads=4) + bias + LN + ELU ----------------
__global__ __launch_bounds__(256) void agg4_k(const float* __restrict__ h,
    const float* __restrict__ as_,const float* __restrict__ ad_,
    const int* __restrict__ offs,const int* __restrict__ ssrc,
    const float* __restrict__ bias,const float* __restrict__ g,const float* __restrict__ be,
    float* __restrict__ out,int N){
  int lane=threadIdx.x&63, wv=threadIdx.x>>6;
  int n=blockIdx.x*4+wv; if(n>=N) return;
  float ad[4], es[4];
  #pragma unroll
  for(int k=0;k<4;k++) ad[k]=ad_[n*4+k];
  #pragma unroll
  for(int k=0;k<4;k++) es[k]=lrelu(as_[n*4+k]+ad[k]);
  int o0=offs[n],o1=offs[n+1];
  float m[4];
  #pragma unroll
  for(int k=0;k<4;k++) m[k]=es[k];
  { // max sweep (lane-parallel over edges)
    float lm[4]={-1e30f,-1e30f,-1e30f,-1e30f};
    for(int j=o0+lane;j<o1;j+=64){
      int s=ssrc[j];
      #pragma unroll
      for(int k=0;k<4;k++) lm[k]=fmaxf(lm[k],lrelu(as_[s*4+k]+ad[k]));
    }
    #pragma unroll
    for(int k=0;k<4;k++) m[k]=fmaxf(m[k],wred_max(lm[k]));
  }
  float inv[4];
  { // denom sweep
    float lz[4]={0.f,0.f,0.f,0.f};
    for(int j=o0+lane;j<o1;j+=64){
      int s=ssrc[j];
      #pragma unroll
      for(int k=0;k<4;k++) lz[k]+=expf(lrelu(as_[s*4+k]+ad[k])-m[k]);
    }
    #pragma unroll
    for(int k=0;k<4;k++){
      float z=wred_sum(lz[k])+expf(es[k]-m[k]);
      inv[k]=1.f/(z+1e-16f);
    }
  }
  float acc[4];
  #pragma unroll
  for(int k=0;k<4;k++){ // self-loop
    float w=expf(es[k]-m[k])*inv[k];
    acc[k]=w*h[(size_t)n*256+k*64+lane];
  }
  for(int j=o0;j<o1;j++){ // sequential edges, all lanes gather channels
    int s=ssrc[j];
    const float* hs=h+(size_t)s*256;
    #pragma unroll
    for(int k=0;k<4;k++){
      float w=expf(lrelu(as_[s*4+k]+ad[k])-m[k])*inv[k];
      acc[k]+=w*hs[k*64+lane];
    }
  }
  #pragma unroll
  for(int k=0;k<4;k++) acc[k]+=bias[k*64+lane];
  // LayerNorm over 256 + ELU
  float tot=wred_sum(acc[0]+acc[1]+acc[2]+acc[3]);
  float mu=tot*(1.f/256.f);
  float vs=0.f;
  #pragma unroll
  for(int k=0;k<4;k++){ float d=acc[k]-mu; vs+=d*d; }
  float var=wred_sum(vs)*(1.f/256.f);
  float r=rsqrtf(var+1e-5f);
  #pragma unroll
  for(int k=0;k<4;k++){
    float v=(acc[k]-mu)*r*g[k*64+lane]+be[k*64+lane];
    out[(size_t)n*256+k*64+lane]= v>0.f? v : expm1f(v);
  }
}

// ---------------- aggregation (heads=1, ch=32) + bias -> d_out ----------------
__global__ __launch_bounds__(256) void agg1_k(const float* __restrict__ h,
    const float* __restrict__ as_,const float* __restrict__ ad_,
    const int* __restrict__ offs,const int* __restrict__ ssrc,
    const float* __restrict__ bias,float* __restrict__ out,int N){
  int lane=threadIdx.x&63, wv=threadIdx.x>>6;
  int n=blockIdx.x*4+wv; if(n>=N) return;
  float ad=ad_[n];
  float es=lrelu(as_[n]+ad);
  int o0=offs[n],o1=offs[n+1];
  float m=es;
  {
    float lm=-1e30f;
    for(int j=o0+lane;j<o1;j+=64) lm=fmaxf(lm,lrelu(as_[ssrc[j]]+ad));
    m=fmaxf(m,wred_max(lm));
  }
  float inv;
  {
    float lz=0.f;
    for(int j=o0+lane;j<o1;j+=64) lz+=expf(lrelu(as_[ssrc[j]]+ad)-m);
    float z=wred_sum(lz)+expf(es-m);
    inv=1.f/(z+1e-16f);
  }
  float acc=0.f;
  if(lane<32) acc=expf(es-m)*inv*h[(size_t)n*32+lane];
  for(int j=o0;j<o1;j++){
    int s=ssrc[j];
    float w=expf(lrelu(as_[s]+ad)-m)*inv;
    if(lane<32) acc+=w*h[(size_t)s*32+lane];
  }
  if(lane<32) out[(size_t)n*32+lane]=acc+bias[lane];
}

extern "C" void kernel_launch(void* const* d_in,const int* in_sizes,int n_in,
                              void* d_out,int out_size,void* d_ws,size_t ws_size,
                              hipStream_t stream){
  const float* x  =(const float*)d_in[0];
  const int*   ei =(const int*)  d_in[1];
  const float* W1 =(const float*)d_in[2];
  const float* a1s=(const float*)d_in[3];
  const float* a1d=(const float*)d_in[4];
  const float* b1 =(const float*)d_in[5];
  const float* g1 =(const float*)d_in[6];
  const float* be1=(const float*)d_in[7];
  const float* W2 =(const float*)d_in[8];
  const float* a2s=(const float*)d_in[9];
  const float* a2d=(const float*)d_in[10];
  const float* b2 =(const float*)d_in[11];
  const float* g2 =(const float*)d_in[12];
  const float* be2=(const float*)d_in[13];
  const float* W3 =(const float*)d_in[14];
  const float* a3s=(const float*)d_in[15];
  const float* a3d=(const float*)d_in[16];
  const float* b3 =(const float*)d_in[17];
  float* outp=(float*)d_out;
  int N=NN;
  int E=in_sizes[1]/2;
  const int* srcA=ei;
  const int* dstA=ei+E;

  char* w=(char*)d_ws;
  float* hbuf=(float*)w; w+=(size_t)N*256*4;
  float* obuf=(float*)w; w+=(size_t)N*256*4;
  float* asb =(float*)w; w+=(size_t)N*4*4;
  float* adb =(float*)w; w+=(size_t)N*4*4;
  int* offs=(int*)w; w+=(size_t)(N+1)*4;
  int* cur =(int*)w; w+=(size_t)N*4;
  int* ssrc=(int*)w; w+=(size_t)E*4;

  // CSR by dst (graph is identical across layers)
  hipMemsetAsync(cur,0,(size_t)N*4,stream);
  hist_k<<<(E+255)/256,256,0,stream>>>(dstA,cur,E);
  scan_k<<<1,1024,0,stream>>>(cur,offs,N,E);
  hipMemsetAsync(cur,0,(size_t)N*4,stream);
  scatter_k<<<(E+255)/256,256,0,stream>>>(srcA,dstA,offs,cur,ssrc,E);

  int nblkN=(N+3)/4;          // 12500
  int gemmY=(N+63)/64;        // 782

  // layer 1: x[50000,128] @ W1[128,256]
  gemm_k<<<dim3(4,gemmY),256,0,stream>>>(x,W1,hbuf,N,256,128);
  attdot4_k<<<nblkN,256,0,stream>>>(hbuf,a1s,a1d,asb,adb,N);
  agg4_k<<<nblkN,256,0,stream>>>(hbuf,asb,adb,offs,ssrc,b1,g1,be1,obuf,N);

  // layer 2: obuf[50000,256] @ W2[256,256]
  gemm_k<<<dim3(4,gemmY),256,0,stream>>>(obuf,W2,hbuf,N,256,256);
  attdot4_k<<<nblkN,256,0,stream>>>(hbuf,a2s,a2d,asb,adb,N);
  agg4_k<<<nblkN,256,0,stream>>>(hbuf,asb,adb,offs,ssrc,b2,g2,be2,obuf,N);

  // layer 3: obuf[50000,256] @ W3[256,32]
  gemm_k<<<dim3(1,gemmY),256,0,stream>>>(obuf,W3,hbuf,N,32,256);
  attdot1_k<<<nblkN,256,0,stream>>>(hbuf,a3s,a3d,asb,adb,N);
  agg1_k<<<nblkN,256,0,stream>>>(hbuf,asb,adb,offs,ssrc,b3,outp,N);
}

// Round 2
// 722.580 us; speedup vs baseline: 1.3551x; 1.3551x over previous
//
#include <hip/hip_runtime.h>
#include <math.h>

#define NN 50000

typedef __attribute__((ext_vector_type(8))) short bf16x8;
typedef __attribute__((ext_vector_type(4))) float f32x4;

__device__ inline float wred_max(float v){
  #pragma unroll
  for(int s=32;s>0;s>>=1) v=fmaxf(v,__shfl_xor(v,s,64));
  return v;
}
__device__ inline float wred_sum(float v){
  #pragma unroll
  for(int s=32;s>0;s>>=1) v+=__shfl_xor(v,s,64);
  return v;
}
__device__ inline float lrelu(float x){ return x>0.f? x : 0.2f*x; }

__device__ inline ushort f2bf(float f){
  union{float f;unsigned u;} v; v.f=f;
  unsigned u=v.u;
  return (ushort)((u + 0x7fffu + ((u>>16)&1u)) >> 16);
}

// ---------------- casts ----------------
__global__ void castrow_k(const float* __restrict__ in, ushort* __restrict__ out, int n){
  int i=blockIdx.x*blockDim.x+threadIdx.x;
  if(i<n) out[i]=f2bf(in[i]);
}
// W[K,N] f32 -> Wt[N,K] bf16
__global__ void casttr_k(const float* __restrict__ W, ushort* __restrict__ Wt, int K, int N){
  int i=blockIdx.x*blockDim.x+threadIdx.x;
  if(i<K*N){ int k=i/N, n=i%N; Wt[n*K+k]=f2bf(W[i]); }
}

// ---------------- CSR build ----------------
__global__ void hist_k(const int* __restrict__ dstA,int* __restrict__ counts,int E){
  int i=blockIdx.x*blockDim.x+threadIdx.x;
  if(i<E) atomicAdd(&counts[dstA[i]],1);
}

__global__ void scan_k(const int* __restrict__ counts,int* __restrict__ offs,int N,int E){
  __shared__ int sd[1024];
  __shared__ int srun;
  int t=threadIdx.x;
  if(t==0) srun=0;
  __syncthreads();
  for(int base=0;base<N;base+=1024){
    int v=(base+t<N)?counts[base+t]:0;
    sd[t]=v;
    __syncthreads();
    for(int s=1;s<1024;s<<=1){
      int a=(t>=s)?sd[t-s]:0;
      __syncthreads();
      sd[t]+=a;
      __syncthreads();
    }
    int run=srun;
    if(base+t<N) offs[base+t]=run+sd[t]-v;  // exclusive prefix
    __syncthreads();
    if(t==1023) srun=run+sd[1023];
    __syncthreads();
  }
  if(t==0) offs[N]=E;
}

__global__ void scatter_k(const int* __restrict__ srcA,const int* __restrict__ dstA,
                          const int* __restrict__ offs,int* cur,int* __restrict__ ssrc,int E){
  int i=blockIdx.x*blockDim.x+threadIdx.x;
  if(i<E){ int d=dstA[i]; int p=offs[d]+atomicAdd(&cur[d],1); ssrc[p]=srcA[i]; }
}

// ---------------- bf16 MFMA GEMM: C[M,N] = A[M,K] @ Bt[N,K]^T ----------------
// A row-major bf16, Bt row-major bf16 (pre-transposed weights), C f32.
// BM = WR*MI*16 (=128), BN = WC*NI*16. BK=32. 256 threads = 4 waves.
template<int WR,int WC,int MI,int NI>
__global__ __launch_bounds__(256) void gemm_bf16_k(const ushort* __restrict__ A,
    const ushort* __restrict__ Bt, float* __restrict__ C, int M, int N, int K){
  constexpr int BM = WR*MI*16;
  constexpr int BN = WC*NI*16;
  constexpr int LDK = 40;  // +8 pad: stride 80B -> conflict-free-ish ds_read_b128
  __shared__ ushort sA[BM*LDK];
  __shared__ ushort sB[BN*LDK];
  int tid=threadIdx.x;
  int lane=tid&63, w=tid>>6;
  int wr=w/WC, wc=w%WC;
  int bm=blockIdx.y*BM, bn=blockIdx.x*BN;
  f32x4 acc[MI][NI]={};

  for(int k0=0;k0<K;k0+=32){
    // stage A: BM rows x 32 bf16 (64B = 4 x 16B chunks per row)
    #pragma unroll
    for(int i=0;i<(BM*4)/256;i++){
      int c=tid+i*256;
      int r=c>>2, cc=c&3;
      int gr=bm+r;
      ulonglong2 v; v.x=0; v.y=0;
      if(gr<M) v=*(const ulonglong2*)(A+(size_t)gr*K+k0+cc*8);
      *(ulonglong2*)(sA+r*LDK+cc*8)=v;
    }
    // stage Bt: BN rows x 32 bf16 (N is a multiple of BN -> no bounds check)
    if constexpr ((BN*4)>=256){
      #pragma unroll
      for(int i=0;i<(BN*4)/256;i++){
        int c=tid+i*256;
        int r=c>>2, cc=c&3;
        ulonglong2 v=*(const ulonglong2*)(Bt+(size_t)(bn+r)*K+k0+cc*8);
        *(ulonglong2*)(sB+r*LDK+cc*8)=v;
      }
    } else {
      if(tid<BN*4){
        int r=tid>>2, cc=tid&3;
        ulonglong2 v=*(const ulonglong2*)(Bt+(size_t)(bn+r)*K+k0+cc*8);
        *(ulonglong2*)(sB+r*LDK+cc*8)=v;
      }
    }
    __syncthreads();
    bf16x8 af[MI], bf[NI];
    #pragma unroll
    for(int m=0;m<MI;m++)
      af[m]=*(bf16x8*)(sA+((wr*MI+m)*16+(lane&15))*LDK+(lane>>4)*8);
    #pragma unroll
    for(int n=0;n<NI;n++)
      bf[n]=*(bf16x8*)(sB+((wc*NI+n)*16+(lane&15))*LDK+(lane>>4)*8);
    #pragma unroll
    for(int m=0;m<MI;m++)
      #pragma unroll
      for(int n=0;n<NI;n++)
        acc[m][n]=__builtin_amdgcn_mfma_f32_16x16x32_bf16(af[m],bf[n],acc[m][n],0,0,0);
    __syncthreads();
  }
  // epilogue: D row=(lane>>4)*4+i, col=lane&15
  int rb=lane>>4, cl=lane&15;
  #pragma unroll
  for(int m=0;m<MI;m++){
    #pragma unroll
    for(int i=0;i<4;i++){
      int gr=bm+(wr*MI+m)*16+rb*4+i;
      if(gr<M){
        #pragma unroll
        for(int n=0;n<NI;n++){
          int gc=bn+(wc*NI+n)*16+cl;
          C[(size_t)gr*N+gc]=acc[m][n][i];
        }
      }
    }
  }
}

// ---------------- attention dot products ----------------
__global__ __launch_bounds__(256) void attdot4_k(const float* __restrict__ h,
    const float* __restrict__ aS,const float* __restrict__ aD,
    float* __restrict__ as_,float* __restrict__ ad_,int N){
  int lane=threadIdx.x&63, wv=threadIdx.x>>6;
  int n=blockIdx.x*4+wv;
  if(n>=N) return;
  const float* hn=h+(size_t)n*256;
  float ps[4],pd[4];
  #pragma unroll
  for(int k=0;k<4;k++){ float v=hn[k*64+lane]; ps[k]=v*aS[k*64+lane]; pd[k]=v*aD[k*64+lane]; }
  #pragma unroll
  for(int k=0;k<4;k++){ ps[k]=wred_sum(ps[k]); pd[k]=wred_sum(pd[k]); }
  if(lane==0){
    #pragma unroll
    for(int k=0;k<4;k++){ as_[n*4+k]=ps[k]; ad_[n*4+k]=pd[k]; }
  }
}

__global__ __launch_bounds__(256) void attdot1_k(const float* __restrict__ h,
    const float* __restrict__ aS,const float* __restrict__ aD,
    float* __restrict__ as_,float* __restrict__ ad_,int N){
  int lane=threadIdx.x&63, wv=threadIdx.x>>6;
  int n=blockIdx.x*4+wv; if(n>=N) return;
  float v=(lane<32)?h[(size_t)n*32+lane]:0.f;
  float ps=(lane<32)?v*aS[lane]:0.f;
  float pd=(lane<32)?v*aD[lane]:0.f;
  ps=wred_sum(ps); pd=wred_sum(pd);
  if(lane==0){ as_[n]=ps; ad_[n]=pd; }
}

// ---------------- aggregation (heads=4) + bias + LN + ELU (dual store) ----------------
__global__ __launch_bounds__(256) void agg4_k(const float* __restrict__ h,
    const float* __restrict__ as_,const float* __restrict__ ad_,
    const int* __restrict__ offs,const int* __restrict__ ssrc,
    const float* __restrict__ bias,const float* __restrict__ g,const float* __restrict__ be,
    float* __restrict__ out,ushort* __restrict__ outb,int N){
  int lane=threadIdx.x&63, wv=threadIdx.x>>6;
  int n=blockIdx.x*4+wv; if(n>=N) return;
  float ad[4], es[4];
  #pragma unroll
  for(int k=0;k<4;k++) ad[k]=ad_[n*4+k];
  #pragma unroll
  for(int k=0;k<4;k++) es[k]=lrelu(as_[n*4+k]+ad[k]);
  int o0=offs[n],o1=offs[n+1];
  float m[4];
  #pragma unroll
  for(int k=0;k<4;k++) m[k]=es[k];
  {
    float lm[4]={-1e30f,-1e30f,-1e30f,-1e30f};
    for(int j=o0+lane;j<o1;j+=64){
      int s=ssrc[j];
      #pragma unroll
      for(int k=0;k<4;k++) lm[k]=fmaxf(lm[k],lrelu(as_[s*4+k]+ad[k]));
    }
    #pragma unroll
    for(int k=0;k<4;k++) m[k]=fmaxf(m[k],wred_max(lm[k]));
  }
  float inv[4];
  {
    float lz[4]={0.f,0.f,0.f,0.f};
    for(int j=o0+lane;j<o1;j+=64){
      int s=ssrc[j];
      #pragma unroll
      for(int k=0;k<4;k++) lz[k]+=expf(lrelu(as_[s*4+k]+ad[k])-m[k]);
    }
    #pragma unroll
    for(int k=0;k<4;k++){
      float z=wred_sum(lz[k])+expf(es[k]-m[k]);
      inv[k]=1.f/(z+1e-16f);
    }
  }
  float acc[4];
  #pragma unroll
  for(int k=0;k<4;k++){
    float w=expf(es[k]-m[k])*inv[k];
    acc[k]=w*h[(size_t)n*256+k*64+lane];
  }
  for(int j=o0;j<o1;j++){
    int s=ssrc[j];
    const float* hs=h+(size_t)s*256;
    #pragma unroll
    for(int k=0;k<4;k++){
      float w=expf(lrelu(as_[s*4+k]+ad[k])-m[k])*inv[k];
      acc[k]+=w*hs[k*64+lane];
    }
  }
  #pragma unroll
  for(int k=0;k<4;k++) acc[k]+=bias[k*64+lane];
  float tot=wred_sum(acc[0]+acc[1]+acc[2]+acc[3]);
  float mu=tot*(1.f/256.f);
  float vs=0.f;
  #pragma unroll
  for(int k=0;k<4;k++){ float d=acc[k]-mu; vs+=d*d; }
  float var=wred_sum(vs)*(1.f/256.f);
  float r=rsqrtf(var+1e-5f);
  #pragma unroll
  for(int k=0;k<4;k++){
    float v=(acc[k]-mu)*r*g[k*64+lane]+be[k*64+lane];
    float ev= v>0.f? v : expm1f(v);
    out[(size_t)n*256+k*64+lane]=ev;
    outb[(size_t)n*256+k*64+lane]=f2bf(ev);
  }
}

// ---------------- aggregation (heads=1, ch=32) + bias -> d_out ----------------
__global__ __launch_bounds__(256) void agg1_k(const float* __restrict__ h,
    const float* __restrict__ as_,const float* __restrict__ ad_,
    const int* __restrict__ offs,const int* __restrict__ ssrc,
    const float* __restrict__ bias,float* __restrict__ out,int N){
  int lane=threadIdx.x&63, wv=threadIdx.x>>6;
  int n=blockIdx.x*4+wv; if(n>=N) return;
  float ad=ad_[n];
  float es=lrelu(as_[n]+ad);
  int o0=offs[n],o1=offs[n+1];
  float m=es;
  {
    float lm=-1e30f;
    for(int j=o0+lane;j<o1;j+=64) lm=fmaxf(lm,lrelu(as_[ssrc[j]]+ad));
    m=fmaxf(m,wred_max(lm));
  }
  float inv;
  {
    float lz=0.f;
    for(int j=o0+lane;j<o1;j+=64) lz+=expf(lrelu(as_[ssrc[j]]+ad)-m);
    float z=wred_sum(lz)+expf(es-m);
    inv=1.f/(z+1e-16f);
  }
  float acc=0.f;
  if(lane<32) acc=expf(es-m)*inv*h[(size_t)n*32+lane];
  for(int j=o0;j<o1;j++){
    int s=ssrc[j];
    float w=expf(lrelu(as_[s]+ad)-m)*inv;
    if(lane<32) acc+=w*h[(size_t)s*32+lane];
  }
  if(lane<32) out[(size_t)n*32+lane]=acc+bias[lane];
}

extern "C" void kernel_launch(void* const* d_in,const int* in_sizes,int n_in,
                              void* d_out,int out_size,void* d_ws,size_t ws_size,
                              hipStream_t stream){
  const float* x  =(const float*)d_in[0];
  const int*   ei =(const int*)  d_in[1];
  const float* W1 =(const float*)d_in[2];
  const float* a1s=(const float*)d_in[3];
  const float* a1d=(const float*)d_in[4];
  const float* b1 =(const float*)d_in[5];
  const float* g1 =(const float*)d_in[6];
  const float* be1=(const float*)d_in[7];
  const float* W2 =(const float*)d_in[8];
  const float* a2s=(const float*)d_in[9];
  const float* a2d=(const float*)d_in[10];
  const float* b2 =(const float*)d_in[11];
  const float* g2 =(const float*)d_in[12];
  const float* be2=(const float*)d_in[13];
  const float* W3 =(const float*)d_in[14];
  const float* a3s=(const float*)d_in[15];
  const float* a3d=(const float*)d_in[16];
  const float* b3 =(const float*)d_in[17];
  float* outp=(float*)d_out;
  int N=NN;
  int E=in_sizes[1]/2;
  const int* srcA=ei;
  const int* dstA=ei+E;

  char* w=(char*)d_ws;
  float* hbuf=(float*)w; w+=(size_t)N*256*4;
  float* obuf=(float*)w; w+=(size_t)N*256*4;
  ushort* obb=(ushort*)w; w+=(size_t)N*256*2;
  ushort* xb =(ushort*)w; w+=(size_t)N*128*2;
  ushort* w1t=(ushort*)w; w+=(size_t)256*128*2;
  ushort* w2t=(ushort*)w; w+=(size_t)256*256*2;
  ushort* w3t=(ushort*)w; w+=(size_t)32*256*2;
  float* asb =(float*)w; w+=(size_t)N*4*4;
  float* adb =(float*)w; w+=(size_t)N*4*4;
  int* offs=(int*)w; w+=(size_t)(N+1)*4;
  int* cur =(int*)w; w+=(size_t)N*4;
  int* ssrc=(int*)w; w+=(size_t)E*4;

  // CSR by dst (graph identical across layers)
  hipMemsetAsync(cur,0,(size_t)N*4,stream);
  hist_k<<<(E+255)/256,256,0,stream>>>(dstA,cur,E);
  scan_k<<<1,1024,0,stream>>>(cur,offs,N,E);
  hipMemsetAsync(cur,0,(size_t)N*4,stream);
  scatter_k<<<(E+255)/256,256,0,stream>>>(srcA,dstA,offs,cur,ssrc,E);

  // casts
  castrow_k<<<(N*128+255)/256,256,0,stream>>>(x,xb,N*128);
  casttr_k<<<(128*256+255)/256,256,0,stream>>>(W1,w1t,128,256);
  casttr_k<<<(256*256+255)/256,256,0,stream>>>(W2,w2t,256,256);
  casttr_k<<<(256*32+255)/256,256,0,stream>>>(W3,w3t,256,32);

  int nblkN=(N+3)/4;          // 12500
  int gemmY=(N+127)/128;      // 391

  // layer 1: xb[50000,128] @ W1t[256,128]^T
  gemm_bf16_k<2,2,4,4><<<dim3(2,gemmY),256,0,stream>>>(xb,w1t,hbuf,N,256,128);
  attdot4_k<<<nblkN,256,0,stream>>>(hbuf,a1s,a1d,asb,adb,N);
  agg4_k<<<nblkN,256,0,stream>>>(hbuf,asb,adb,offs,ssrc,b1,g1,be1,obuf,obb,N);

  // layer 2: obb[50000,256] @ W2t[256,256]^T
  gemm_bf16_k<2,2,4,4><<<dim3(2,gemmY),256,0,stream>>>(obb,w2t,hbuf,N,256,256);
  attdot4_k<<<nblkN,256,0,stream>>>(hbuf,a2s,a2d,asb,adb,N);
  agg4_k<<<nblkN,256,0,stream>>>(hbuf,asb,adb,offs,ssrc,b2,g2,be2,obuf,obb,N);

  // layer 3: obb[50000,256] @ W3t[32,256]^T
  gemm_bf16_k<4,1,2,2><<<dim3(1,gemmY),256,0,stream>>>(obb,w3t,hbuf,N,32,256);
  attdot1_k<<<nblkN,256,0,stream>>>(hbuf,a3s,a3d,asb,adb,N);
  agg1_k<<<nblkN,256,0,stream>>>(hbuf,asb,adb,offs,ssrc,b3,outp,N);
}

// Round 3
// 559.245 us; speedup vs baseline: 1.7509x; 1.2921x over previous
//
#include <hip/hip_runtime.h>
#include <math.h>

#define NN 50000

typedef __attribute__((ext_vector_type(8))) short bf16x8;
typedef __attribute__((ext_vector_type(4))) float f32x4;

__device__ inline float wred_max(float v){
  #pragma unroll
  for(int s=32;s>0;s>>=1) v=fmaxf(v,__shfl_xor(v,s,64));
  return v;
}
__device__ inline float wred_sum(float v){
  #pragma unroll
  for(int s=32;s>0;s>>=1) v+=__shfl_xor(v,s,64);
  return v;
}
__device__ inline float lrelu(float x){ return x>0.f? x : 0.2f*x; }
__device__ inline float rlf(float v,int l){ return __int_as_float(__builtin_amdgcn_readlane(__float_as_int(v),l)); }

__device__ inline ushort f2bf(float f){
  union{float f;unsigned u;} v; v.f=f;
  unsigned u=v.u;
  return (ushort)((u + 0x7fffu + ((u>>16)&1u)) >> 16);
}

// ---------------- casts ----------------
__global__ void castrow_k(const float* __restrict__ in, ushort* __restrict__ out, int n){
  int i=blockIdx.x*blockDim.x+threadIdx.x;
  if(i<n) out[i]=f2bf(in[i]);
}
// W[K,N] f32 -> Wt[N,K] bf16
__global__ void casttr_k(const float* __restrict__ W, ushort* __restrict__ Wt, int K, int N){
  int i=blockIdx.x*blockDim.x+threadIdx.x;
  if(i<K*N){ int k=i/N, n=i%N; Wt[n*K+k]=f2bf(W[i]); }
}

// ---------------- CSR build ----------------
__global__ void hist_k(const int* __restrict__ dstA,int* __restrict__ counts,int E){
  int i=blockIdx.x*blockDim.x+threadIdx.x;
  if(i<E) atomicAdd(&counts[dstA[i]],1);
}

// shfl-based single-block scan (3 barriers/KiB-tile instead of ~25)
__global__ __launch_bounds__(1024) void scan_k(const int* __restrict__ counts,int* __restrict__ offs,int N,int E){
  __shared__ int stot[16];
  __shared__ int sbase;
  int t=threadIdx.x; int lane=t&63, wv=t>>6;
  if(t==0) sbase=0;
  __syncthreads();
  for(int base=0;base<N;base+=1024){
    int orig=(base+t<N)?counts[base+t]:0;
    int v=orig;
    #pragma unroll
    for(int s=1;s<64;s<<=1){ int u=__shfl_up(v,s,64); if(lane>=s) v+=u; }
    if(lane==63) stot[wv]=v;
    __syncthreads();
    if(wv==0){
      int tv=(lane<16)?stot[lane]:0;
      #pragma unroll
      for(int s=1;s<16;s<<=1){ int u=__shfl_up(tv,s,64); if(lane>=s) tv+=u; }
      if(lane<16) stot[lane]=tv;
    }
    __syncthreads();
    int run=sbase;
    int wpref=(wv>0)?stot[wv-1]:0;
    if(base+t<N) offs[base+t]=run+wpref+v-orig;  // exclusive prefix
    __syncthreads();
    if(t==1023) sbase=run+stot[15];
    __syncthreads();
  }
  if(threadIdx.x==0) offs[N]=E;
}

__global__ void scatter_k(const int* __restrict__ srcA,const int* __restrict__ dstA,
                          const int* __restrict__ offs,int* cur,int* __restrict__ ssrc,int E){
  int i=blockIdx.x*blockDim.x+threadIdx.x;
  if(i<E){ int d=dstA[i]; int p=offs[d]+atomicAdd(&cur[d],1); ssrc[p]=srcA[i]; }
}

// ---------------- bf16 MFMA GEMM: C[M,N] = A[M,K] @ Bt[N,K]^T ----------------
// PERM=1: write C permuted within each 128-col block-half:
//   pos = bn + 2*(gc&63) + ((gc>>6)&1)   (so channel k*64+l sits at l*2+(k&1) in half k>>1)
template<int WR,int WC,int MI,int NI,int PERM>
__global__ __launch_bounds__(256) void gemm_bf16_k(const ushort* __restrict__ A,
    const ushort* __restrict__ Bt, float* __restrict__ C, int M, int N, int K){
  constexpr int BM = WR*MI*16;
  constexpr int BN = WC*NI*16;
  constexpr int LDK = 40;
  __shared__ ushort sA[BM*LDK];
  __shared__ ushort sB[BN*LDK];
  int tid=threadIdx.x;
  int lane=tid&63, w=tid>>6;
  int wr=w/WC, wc=w%WC;
  int bm=blockIdx.y*BM, bn=blockIdx.x*BN;
  f32x4 acc[MI][NI]={};

  for(int k0=0;k0<K;k0+=32){
    #pragma unroll
    for(int i=0;i<(BM*4)/256;i++){
      int c=tid+i*256;
      int r=c>>2, cc=c&3;
      int gr=bm+r;
      ulonglong2 v; v.x=0; v.y=0;
      if(gr<M) v=*(const ulonglong2*)(A+(size_t)gr*K+k0+cc*8);
      *(ulonglong2*)(sA+r*LDK+cc*8)=v;
    }
    if constexpr ((BN*4)>=256){
      #pragma unroll
      for(int i=0;i<(BN*4)/256;i++){
        int c=tid+i*256;
        int r=c>>2, cc=c&3;
        ulonglong2 v=*(const ulonglong2*)(Bt+(size_t)(bn+r)*K+k0+cc*8);
        *(ulonglong2*)(sB+r*LDK+cc*8)=v;
      }
    } else {
      if(tid<BN*4){
        int r=tid>>2, cc=tid&3;
        ulonglong2 v=*(const ulonglong2*)(Bt+(size_t)(bn+r)*K+k0+cc*8);
        *(ulonglong2*)(sB+r*LDK+cc*8)=v;
      }
    }
    __syncthreads();
    bf16x8 af[MI], bf[NI];
    #pragma unroll
    for(int m=0;m<MI;m++)
      af[m]=*(bf16x8*)(sA+((wr*MI+m)*16+(lane&15))*LDK+(lane>>4)*8);
    #pragma unroll
    for(int n=0;n<NI;n++)
      bf[n]=*(bf16x8*)(sB+((wc*NI+n)*16+(lane&15))*LDK+(lane>>4)*8);
    #pragma unroll
    for(int m=0;m<MI;m++)
      #pragma unroll
      for(int n=0;n<NI;n++)
        acc[m][n]=__builtin_amdgcn_mfma_f32_16x16x32_bf16(af[m],bf[n],acc[m][n],0,0,0);
    __syncthreads();
  }
  int rb=lane>>4, cl=lane&15;
  #pragma unroll
  for(int m=0;m<MI;m++){
    #pragma unroll
    for(int i=0;i<4;i++){
      int gr=bm+(wr*MI+m)*16+rb*4+i;
      if(gr<M){
        #pragma unroll
        for(int n=0;n<NI;n++){
          int gc=bn+(wc*NI+n)*16+cl;
          int pos = PERM ? (bn + 2*(gc&63) + ((gc>>6)&1)) : gc;
          C[(size_t)gr*N+pos]=acc[m][n][i];
        }
      }
    }
  }
}

// ---------------- attention dots (heads=4, permuted h layout) ----------------
__global__ __launch_bounds__(256) void attdot4_k(const float* __restrict__ h,
    const float* __restrict__ aS,const float* __restrict__ aD,
    float* __restrict__ as_,float* __restrict__ ad_,int N){
  int lane=threadIdx.x&63, wv=threadIdx.x>>6;
  int n=blockIdx.x*4+wv;
  if(n>=N) return;
  const float* hn=h+(size_t)n*256;
  float2 p0=*(const float2*)(hn+lane*2);
  float2 p1=*(const float2*)(hn+128+lane*2);
  float v[4]={p0.x,p0.y,p1.x,p1.y};
  float ps[4],pd[4];
  #pragma unroll
  for(int k=0;k<4;k++){ ps[k]=v[k]*aS[k*64+lane]; pd[k]=v[k]*aD[k*64+lane]; }
  #pragma unroll
  for(int k=0;k<4;k++){ ps[k]=wred_sum(ps[k]); pd[k]=wred_sum(pd[k]); }
  if(lane==0){
    #pragma unroll
    for(int k=0;k<4;k++){ as_[n*4+k]=ps[k]; ad_[n*4+k]=pd[k]; }
  }
}

__global__ __launch_bounds__(256) void attdot1_k(const float* __restrict__ h,
    const float* __restrict__ aS,const float* __restrict__ aD,
    float* __restrict__ as_,float* __restrict__ ad_,int N){
  int lane=threadIdx.x&63, wv=threadIdx.x>>6;
  int n=blockIdx.x*4+wv; if(n>=N) return;
  float v=(lane<32)?h[(size_t)n*32+lane]:0.f;
  float ps=(lane<32)?v*aS[lane]:0.f;
  float pd=(lane<32)?v*aD[lane]:0.f;
  ps=wred_sum(ps); pd=wred_sum(pd);
  if(lane==0){ as_[n]=ps; ad_[n]=pd; }
}

// ---------------- aggregation (heads=4, permuted h) + bias + LN + ELU ----------------
__global__ __launch_bounds__(256) void agg4_k(const float* __restrict__ h,
    const float* __restrict__ as_,const float* __restrict__ ad_,
    const int* __restrict__ offs,const int* __restrict__ ssrc,
    const float* __restrict__ bias,const float* __restrict__ g,const float* __restrict__ be,
    ushort* __restrict__ outb,int N){
  int lane=threadIdx.x&63, wv=threadIdx.x>>6;
  int n=blockIdx.x*4+wv; if(n>=N) return;
  int lane2=lane*2;
  float ad[4], es[4];
  #pragma unroll
  for(int k=0;k<4;k++) ad[k]=ad_[n*4+k];
  #pragma unroll
  for(int k=0;k<4;k++) es[k]=lrelu(as_[n*4+k]+ad[k]);
  int o0=offs[n],o1=offs[n+1];
  float m[4]={es[0],es[1],es[2],es[3]};
  { // max sweep, lane-parallel
    float lm[4]={-1e30f,-1e30f,-1e30f,-1e30f};
    for(int j=o0+lane;j<o1;j+=64){
      int s=ssrc[j];
      float4 av=*(const float4*)(as_+(size_t)s*4);
      float a[4]={av.x,av.y,av.z,av.w};
      #pragma unroll
      for(int k=0;k<4;k++) lm[k]=fmaxf(lm[k],lrelu(a[k]+ad[k]));
    }
    #pragma unroll
    for(int k=0;k<4;k++) m[k]=fmaxf(m[k],wred_max(lm[k]));
  }
  float inv[4];
  { // denom sweep, lane-parallel
    float lz[4]={0.f,0.f,0.f,0.f};
    for(int j=o0+lane;j<o1;j+=64){
      int s=ssrc[j];
      float4 av=*(const float4*)(as_+(size_t)s*4);
      float a[4]={av.x,av.y,av.z,av.w};
      #pragma unroll
      for(int k=0;k<4;k++) lz[k]+=__expf(lrelu(a[k]+ad[k])-m[k]);
    }
    #pragma unroll
    for(int k=0;k<4;k++){
      float z=wred_sum(lz[k])+__expf(es[k]-m[k]);
      inv[k]=1.f/(z+1e-16f);
    }
  }
  // self-loop
  float acc[4];
  {
    const float* hn=h+(size_t)n*256;
    float2 p0=*(const float2*)(hn+lane2);
    float2 p1=*(const float2*)(hn+128+lane2);
    float hv[4]={p0.x,p0.y,p1.x,p1.y};
    #pragma unroll
    for(int k=0;k<4;k++) acc[k]=__expf(es[k]-m[k])*inv[k]*hv[k];
  }
  // chunked accumulate: lane-parallel weights, readlane broadcast, depth-4 pipeline
  for(int base=o0;base<o1;base+=64){
    int cnt=min(64,o1-base);
    int j=base+lane;
    int sv=0; float w4[4]={0.f,0.f,0.f,0.f};
    if(j<o1){
      sv=ssrc[j];
      float4 av=*(const float4*)(as_+(size_t)sv*4);
      float a[4]={av.x,av.y,av.z,av.w};
      #pragma unroll
      for(int k=0;k<4;k++) w4[k]=__expf(lrelu(a[k]+ad[k])-m[k])*inv[k];
    }
    int t=0;
    for(; t+4<=cnt; t+=4){
      int s0=__builtin_amdgcn_readlane(sv,t);
      int s1=__builtin_amdgcn_readlane(sv,t+1);
      int s2=__builtin_amdgcn_readlane(sv,t+2);
      int s3=__builtin_amdgcn_readlane(sv,t+3);
      const float* b0=h+(size_t)s0*256;
      const float* b1=h+(size_t)s1*256;
      const float* b2=h+(size_t)s2*256;
      const float* b3=h+(size_t)s3*256;
      float2 x0=*(const float2*)(b0+lane2), y0=*(const float2*)(b0+128+lane2);
      float2 x1=*(const float2*)(b1+lane2), y1=*(const float2*)(b1+128+lane2);
      float2 x2=*(const float2*)(b2+lane2), y2=*(const float2*)(b2+128+lane2);
      float2 x3=*(const float2*)(b3+lane2), y3=*(const float2*)(b3+128+lane2);
      acc[0]+=rlf(w4[0],t  )*x0.x; acc[1]+=rlf(w4[1],t  )*x0.y; acc[2]+=rlf(w4[2],t  )*y0.x; acc[3]+=rlf(w4[3],t  )*y0.y;
      acc[0]+=rlf(w4[0],t+1)*x1.x; acc[1]+=rlf(w4[1],t+1)*x1.y; acc[2]+=rlf(w4[2],t+1)*y1.x; acc[3]+=rlf(w4[3],t+1)*y1.y;
      acc[0]+=rlf(w4[0],t+2)*x2.x; acc[1]+=rlf(w4[1],t+2)*x2.y; acc[2]+=rlf(w4[2],t+2)*y2.x; acc[3]+=rlf(w4[3],t+2)*y2.y;
      acc[0]+=rlf(w4[0],t+3)*x3.x; acc[1]+=rlf(w4[1],t+3)*x3.y; acc[2]+=rlf(w4[2],t+3)*y3.x; acc[3]+=rlf(w4[3],t+3)*y3.y;
    }
    for(; t<cnt; t++){
      int s0=__builtin_amdgcn_readlane(sv,t);
      const float* b0=h+(size_t)s0*256;
      float2 x0=*(const float2*)(b0+lane2), y0=*(const float2*)(b0+128+lane2);
      acc[0]+=rlf(w4[0],t)*x0.x; acc[1]+=rlf(w4[1],t)*x0.y; acc[2]+=rlf(w4[2],t)*y0.x; acc[3]+=rlf(w4[3],t)*y0.y;
    }
  }
  #pragma unroll
  for(int k=0;k<4;k++) acc[k]+=bias[k*64+lane];
  // LayerNorm over 256 + ELU -> bf16 (standard row-major for next GEMM)
  float tot=wred_sum(acc[0]+acc[1]+acc[2]+acc[3]);
  float mu=tot*(1.f/256.f);
  float vs=0.f;
  #pragma unroll
  for(int k=0;k<4;k++){ float d=acc[k]-mu; vs+=d*d; }
  float var=wred_sum(vs)*(1.f/256.f);
  float r=rsqrtf(var+1e-5f);
  #pragma unroll
  for(int k=0;k<4;k++){
    float v=(acc[k]-mu)*r*g[k*64+lane]+be[k*64+lane];
    float ev= v>0.f? v : expm1f(v);
    outb[(size_t)n*256+k*64+lane]=f2bf(ev);
  }
}

// ---------------- aggregation (heads=1, ch=32, standard h) + bias -> d_out ----------------
__global__ __launch_bounds__(256) void agg1_k(const float* __restrict__ h,
    const float* __restrict__ as_,const float* __restrict__ ad_,
    const int* __restrict__ offs,const int* __restrict__ ssrc,
    const float* __restrict__ bias,float* __restrict__ out,int N){
  int lane=threadIdx.x&63, wv=threadIdx.x>>6;
  int n=blockIdx.x*4+wv; if(n>=N) return;
  float ad=ad_[n];
  float es=lrelu(as_[n]+ad);
  int o0=offs[n],o1=offs[n+1];
  float m=es;
  {
    float lm=-1e30f;
    for(int j=o0+lane;j<o1;j+=64) lm=fmaxf(lm,lrelu(as_[ssrc[j]]+ad));
    m=fmaxf(m,wred_max(lm));
  }
  float inv;
  {
    float lz=0.f;
    for(int j=o0+lane;j<o1;j+=64) lz+=__expf(lrelu(as_[ssrc[j]]+ad)-m);
    float z=wred_sum(lz)+__expf(es-m);
    inv=1.f/(z+1e-16f);
  }
  float acc=0.f;
  if(lane<32) acc=__expf(es-m)*inv*h[(size_t)n*32+lane];
  for(int base=o0;base<o1;base+=64){
    int cnt=min(64,o1-base);
    int j=base+lane;
    int sv=0; float wv1=0.f;
    if(j<o1){
      sv=ssrc[j];
      wv1=__expf(lrelu(as_[sv]+ad)-m)*inv;
    }
    int t=0;
    for(; t+4<=cnt; t+=4){
      int s0=__builtin_amdgcn_readlane(sv,t);
      int s1=__builtin_amdgcn_readlane(sv,t+1);
      int s2=__builtin_amdgcn_readlane(sv,t+2);
      int s3=__builtin_amdgcn_readlane(sv,t+3);
      if(lane<32){
        float h0=h[(size_t)s0*32+lane];
        float h1=h[(size_t)s1*32+lane];
        float h2=h[(size_t)s2*32+lane];
        float h3=h[(size_t)s3*32+lane];
        acc+=rlf(wv1,t)*h0+rlf(wv1,t+1)*h1+rlf(wv1,t+2)*h2+rlf(wv1,t+3)*h3;
      }
    }
    for(; t<cnt; t++){
      int s0=__builtin_amdgcn_readlane(sv,t);
      if(lane<32) acc+=rlf(wv1,t)*h[(size_t)s0*32+lane];
    }
  }
  if(lane<32) out[(size_t)n*32+lane]=acc+bias[lane];
}

extern "C" void kernel_launch(void* const* d_in,const int* in_sizes,int n_in,
                              void* d_out,int out_size,void* d_ws,size_t ws_size,
                              hipStream_t stream){
  const float* x  =(const float*)d_in[0];
  const int*   ei =(const int*)  d_in[1];
  const float* W1 =(const float*)d_in[2];
  const float* a1s=(const float*)d_in[3];
  const float* a1d=(const float*)d_in[4];
  const float* b1 =(const float*)d_in[5];
  const float* g1 =(const float*)d_in[6];
  const float* be1=(const float*)d_in[7];
  const float* W2 =(const float*)d_in[8];
  const float* a2s=(const float*)d_in[9];
  const float* a2d=(const float*)d_in[10];
  const float* b2 =(const float*)d_in[11];
  const float* g2 =(const float*)d_in[12];
  const float* be2=(const float*)d_in[13];
  const float* W3 =(const float*)d_in[14];
  const float* a3s=(const float*)d_in[15];
  const float* a3d=(const float*)d_in[16];
  const float* b3 =(const float*)d_in[17];
  float* outp=(float*)d_out;
  int N=NN;
  int E=in_sizes[1]/2;
  const int* srcA=ei;
  const int* dstA=ei+E;

  char* w=(char*)d_ws;
  float* hbuf=(float*)w; w+=(size_t)N*256*4;
  ushort* obb=(ushort*)w; w+=(size_t)N*256*2;
  ushort* xb =(ushort*)w; w+=(size_t)N*128*2;
  ushort* w1t=(ushort*)w; w+=(size_t)256*128*2;
  ushort* w2t=(ushort*)w; w+=(size_t)256*256*2;
  ushort* w3t=(ushort*)w; w+=(size_t)32*256*2;
  float* asb =(float*)w; w+=(size_t)N*4*4;
  float* adb =(float*)w; w+=(size_t)N*4*4;
  int* offs=(int*)w; w+=(size_t)(N+4)*4;   // padded to keep 16B alignment
  int* cur =(int*)w; w+=(size_t)N*4;
  int* ssrc=(int*)w; w+=(size_t)E*4;

  // CSR by dst (graph identical across layers)
  hipMemsetAsync(cur,0,(size_t)N*4,stream);
  hist_k<<<(E+255)/256,256,0,stream>>>(dstA,cur,E);
  scan_k<<<1,1024,0,stream>>>(cur,offs,N,E);
  hipMemsetAsync(cur,0,(size_t)N*4,stream);
  scatter_k<<<(E+255)/256,256,0,stream>>>(srcA,dstA,offs,cur,ssrc,E);

  // casts
  castrow_k<<<(N*128+255)/256,256,0,stream>>>(x,xb,N*128);
  casttr_k<<<(128*256+255)/256,256,0,stream>>>(W1,w1t,128,256);
  casttr_k<<<(256*256+255)/256,256,0,stream>>>(W2,w2t,256,256);
  casttr_k<<<(256*32+255)/256,256,0,stream>>>(W3,w3t,256,32);

  int nblkN=(N+3)/4;          // 12500
  int gemmY=(N+127)/128;      // 391

  // layer 1: xb[50000,128] @ W1t[256,128]^T  (permuted store)
  gemm_bf16_k<2,2,4,4,1><<<dim3(2,gemmY),256,0,stream>>>(xb,w1t,hbuf,N,256,128);
  attdot4_k<<<nblkN,256,0,stream>>>(hbuf,a1s,a1d,asb,adb,N);
  agg4_k<<<nblkN,256,0,stream>>>(hbuf,asb,adb,offs,ssrc,b1,g1,be1,obb,N);

  // layer 2: obb[50000,256] @ W2t[256,256]^T  (permuted store)
  gemm_bf16_k<2,2,4,4,1><<<dim3(2,gemmY),256,0,stream>>>(obb,w2t,hbuf,N,256,256);
  attdot4_k<<<nblkN,256,0,stream>>>(hbuf,a2s,a2d,asb,adb,N);
  agg4_k<<<nblkN,256,0,stream>>>(hbuf,asb,adb,offs,ssrc,b2,g2,be2,obb,N);

  // layer 3: obb[50000,256] @ W3t[32,256]^T  (standard store)
  gemm_bf16_k<4,1,2,2,0><<<dim3(1,gemmY),256,0,stream>>>(obb,w3t,hbuf,N,32,256);
  attdot1_k<<<nblkN,256,0,stream>>>(hbuf,a3s,a3d,asb,adb,N);
  agg1_k<<<nblkN,256,0,stream>>>(hbuf,asb,adb,offs,ssrc,b3,outp,N);
}

// Round 4
// 484.742 us; speedup vs baseline: 2.0200x; 1.1537x over previous
//
#include <hip/hip_runtime.h>
#include <math.h>

#define NN 50000

typedef __attribute__((ext_vector_type(8))) short bf16x8;
typedef __attribute__((ext_vector_type(4))) float f32x4;

__device__ inline float wred_max(float v){
  #pragma unroll
  for(int s=32;s>0;s>>=1) v=fmaxf(v,__shfl_xor(v,s,64));
  return v;
}
__device__ inline float wred_sum(float v){
  #pragma unroll
  for(int s=32;s>0;s>>=1) v+=__shfl_xor(v,s,64);
  return v;
}
__device__ inline float lrelu(float x){ return x>0.f? x : 0.2f*x; }
__device__ inline float rlf(float v,int l){ return __int_as_float(__builtin_amdgcn_readlane(__float_as_int(v),l)); }

__device__ inline ushort f2bf(float f){
  union{float f;unsigned u;} v; v.f=f;
  unsigned u=v.u;
  return (ushort)((u + 0x7fffu + ((u>>16)&1u)) >> 16);
}
// unpack packed bf16 pair (uint) -> two f32
__device__ inline float bflo(unsigned u){ return __uint_as_float(u<<16); }
__device__ inline float bfhi(unsigned u){ return __uint_as_float(u&0xffff0000u); }

// ---------------- casts ----------------
__global__ void castrow_k(const float* __restrict__ in, ushort* __restrict__ out, int n){
  int i=blockIdx.x*blockDim.x+threadIdx.x;
  if(i<n) out[i]=f2bf(in[i]);
}
// W[K,N] f32 -> Wt[N,K] bf16
__global__ void casttr_k(const float* __restrict__ W, ushort* __restrict__ Wt, int K, int N){
  int i=blockIdx.x*blockDim.x+threadIdx.x;
  if(i<K*N){ int k=i/N, n=i%N; Wt[n*K+k]=f2bf(W[i]); }
}

// ---------------- CSR build ----------------
__global__ void hist_k(const int* __restrict__ dstA,int* __restrict__ counts,int E){
  int i=blockIdx.x*blockDim.x+threadIdx.x;
  if(i<E) atomicAdd(&counts[dstA[i]],1);
}

__global__ __launch_bounds__(1024) void scan_k(const int* __restrict__ counts,int* __restrict__ offs,int N,int E){
  __shared__ int stot[16];
  __shared__ int sbase;
  int t=threadIdx.x; int lane=t&63, wv=t>>6;
  if(t==0) sbase=0;
  __syncthreads();
  for(int base=0;base<N;base+=1024){
    int orig=(base+t<N)?counts[base+t]:0;
    int v=orig;
    #pragma unroll
    for(int s=1;s<64;s<<=1){ int u=__shfl_up(v,s,64); if(lane>=s) v+=u; }
    if(lane==63) stot[wv]=v;
    __syncthreads();
    if(wv==0){
      int tv=(lane<16)?stot[lane]:0;
      #pragma unroll
      for(int s=1;s<16;s<<=1){ int u=__shfl_up(tv,s,64); if(lane>=s) tv+=u; }
      if(lane<16) stot[lane]=tv;
    }
    __syncthreads();
    int run=sbase;
    int wpref=(wv>0)?stot[wv-1]:0;
    if(base+t<N) offs[base+t]=run+wpref+v-orig;
    __syncthreads();
    if(t==1023) sbase=run+stot[15];
    __syncthreads();
  }
  if(threadIdx.x==0) offs[N]=E;
}

__global__ void scatter_k(const int* __restrict__ srcA,const int* __restrict__ dstA,
                          const int* __restrict__ offs,int* cur,int* __restrict__ ssrc,int E){
  int i=blockIdx.x*blockDim.x+threadIdx.x;
  if(i<E){ int d=dstA[i]; int p=offs[d]+atomicAdd(&cur[d],1); ssrc[p]=srcA[i]; }
}

// ---------------- bf16 MFMA GEMM: C = A[M,K] @ Bt[N,K]^T ----------------
// OUTM=0: f32 row-major. OUTM=1: bf16 head-interleaved perm (N must be 256):
//   channel c -> pos 4*(c&63)+(c>>6). OUTM=2: bf16 row-major.
template<int WR,int WC,int MI,int NI,int OUTM>
__global__ __launch_bounds__(256) void gemm_bf16_k(const ushort* __restrict__ A,
    const ushort* __restrict__ Bt, void* __restrict__ Cv, int M, int N, int K){
  constexpr int BM = WR*MI*16;
  constexpr int BN = WC*NI*16;
  constexpr int LDK = 40;
  __shared__ ushort sA[BM*LDK];
  __shared__ ushort sB[BN*LDK];
  int tid=threadIdx.x;
  int lane=tid&63, w=tid>>6;
  int wr=w/WC, wc=w%WC;
  int bm=blockIdx.y*BM, bn=blockIdx.x*BN;
  f32x4 acc[MI][NI]={};

  for(int k0=0;k0<K;k0+=32){
    #pragma unroll
    for(int i=0;i<(BM*4)/256;i++){
      int c=tid+i*256;
      int r=c>>2, cc=c&3;
      int gr=bm+r;
      ulonglong2 v; v.x=0; v.y=0;
      if(gr<M) v=*(const ulonglong2*)(A+(size_t)gr*K+k0+cc*8);
      *(ulonglong2*)(sA+r*LDK+cc*8)=v;
    }
    if constexpr ((BN*4)>=256){
      #pragma unroll
      for(int i=0;i<(BN*4)/256;i++){
        int c=tid+i*256;
        int r=c>>2, cc=c&3;
        ulonglong2 v=*(const ulonglong2*)(Bt+(size_t)(bn+r)*K+k0+cc*8);
        *(ulonglong2*)(sB+r*LDK+cc*8)=v;
      }
    } else {
      if(tid<BN*4){
        int r=tid>>2, cc=tid&3;
        ulonglong2 v=*(const ulonglong2*)(Bt+(size_t)(bn+r)*K+k0+cc*8);
        *(ulonglong2*)(sB+r*LDK+cc*8)=v;
      }
    }
    __syncthreads();
    bf16x8 af[MI], bf[NI];
    #pragma unroll
    for(int m=0;m<MI;m++)
      af[m]=*(bf16x8*)(sA+((wr*MI+m)*16+(lane&15))*LDK+(lane>>4)*8);
    #pragma unroll
    for(int n=0;n<NI;n++)
      bf[n]=*(bf16x8*)(sB+((wc*NI+n)*16+(lane&15))*LDK+(lane>>4)*8);
    #pragma unroll
    for(int m=0;m<MI;m++)
      #pragma unroll
      for(int n=0;n<NI;n++)
        acc[m][n]=__builtin_amdgcn_mfma_f32_16x16x32_bf16(af[m],bf[n],acc[m][n],0,0,0);
    __syncthreads();
  }
  int rb=lane>>4, cl=lane&15;
  #pragma unroll
  for(int m=0;m<MI;m++){
    #pragma unroll
    for(int i=0;i<4;i++){
      int gr=bm+(wr*MI+m)*16+rb*4+i;
      if(gr<M){
        #pragma unroll
        for(int n=0;n<NI;n++){
          int gc=bn+(wc*NI+n)*16+cl;
          if constexpr (OUTM==1){
            ushort* C=(ushort*)Cv;
            int pos=4*(gc&63)+(gc>>6);
            C[(size_t)gr*N+pos]=f2bf(acc[m][n][i]);
          } else if constexpr (OUTM==2){
            ushort* C=(ushort*)Cv;
            C[(size_t)gr*N+gc]=f2bf(acc[m][n][i]);
          } else {
            float* C=(float*)Cv;
            C[(size_t)gr*N+gc]=acc[m][n][i];
          }
        }
      }
    }
  }
}

// ---------------- attention dots (heads=4, bf16 permuted h) ----------------
__global__ __launch_bounds__(256) void attdot4_k(const ushort* __restrict__ hb,
    const float* __restrict__ aS,const float* __restrict__ aD,
    float* __restrict__ as_,float* __restrict__ ad_,int N){
  int lane=threadIdx.x&63, wv=threadIdx.x>>6;
  int n=blockIdx.x*4+wv;
  if(n>=N) return;
  uint2 u=*(const uint2*)(hb+(size_t)n*256+lane*4);
  float v[4]={bflo(u.x),bfhi(u.x),bflo(u.y),bfhi(u.y)};
  float ps[4],pd[4];
  #pragma unroll
  for(int k=0;k<4;k++){ ps[k]=v[k]*aS[k*64+lane]; pd[k]=v[k]*aD[k*64+lane]; }
  #pragma unroll
  for(int k=0;k<4;k++){ ps[k]=wred_sum(ps[k]); pd[k]=wred_sum(pd[k]); }
  if(lane==0){
    #pragma unroll
    for(int k=0;k<4;k++){ as_[n*4+k]=ps[k]; ad_[n*4+k]=pd[k]; }
  }
}

// heads=1, ch=32, bf16 row-major h
__global__ __launch_bounds__(256) void attdot1_k(const ushort* __restrict__ hb,
    const float* __restrict__ aS,const float* __restrict__ aD,
    float* __restrict__ as_,float* __restrict__ ad_,int N){
  int lane=threadIdx.x&63, wv=threadIdx.x>>6;
  int n=blockIdx.x*4+wv; if(n>=N) return;
  float v=(lane<32)?__uint_as_float(((unsigned)hb[(size_t)n*32+lane])<<16):0.f;
  float ps=(lane<32)?v*aS[lane]:0.f;
  float pd=(lane<32)?v*aD[lane]:0.f;
  ps=wred_sum(ps); pd=wred_sum(pd);
  if(lane==0){ as_[n]=ps; ad_[n]=pd; }
}

// ---------------- aggregation (heads=4, bf16 permuted h) + bias + LN + ELU ----------------
__global__ __launch_bounds__(256) void agg4_k(const ushort* __restrict__ hb,
    const float* __restrict__ as_,const float* __restrict__ ad_,
    const int* __restrict__ offs,const int* __restrict__ ssrc,
    const float* __restrict__ bias,const float* __restrict__ g,const float* __restrict__ be,
    ushort* __restrict__ outb,int N){
  int lane=threadIdx.x&63, wv=threadIdx.x>>6;
  int n=blockIdx.x*4+wv; if(n>=N) return;
  int lane4=lane*4;
  float ad[4], es[4];
  #pragma unroll
  for(int k=0;k<4;k++) ad[k]=ad_[n*4+k];
  #pragma unroll
  for(int k=0;k<4;k++) es[k]=lrelu(as_[n*4+k]+ad[k]);
  int o0=offs[n],o1=offs[n+1];
  float m[4]={es[0],es[1],es[2],es[3]};
  { // max sweep
    float lm[4]={-1e30f,-1e30f,-1e30f,-1e30f};
    for(int j=o0+lane;j<o1;j+=64){
      int s=ssrc[j];
      float4 av=*(const float4*)(as_+(size_t)s*4);
      float a[4]={av.x,av.y,av.z,av.w};
      #pragma unroll
      for(int k=0;k<4;k++) lm[k]=fmaxf(lm[k],lrelu(a[k]+ad[k]));
    }
    #pragma unroll
    for(int k=0;k<4;k++) m[k]=fmaxf(m[k],wred_max(lm[k]));
  }
  float inv[4];
  { // denom sweep
    float lz[4]={0.f,0.f,0.f,0.f};
    for(int j=o0+lane;j<o1;j+=64){
      int s=ssrc[j];
      float4 av=*(const float4*)(as_+(size_t)s*4);
      float a[4]={av.x,av.y,av.z,av.w};
      #pragma unroll
      for(int k=0;k<4;k++) lz[k]+=__expf(lrelu(a[k]+ad[k])-m[k]);
    }
    #pragma unroll
    for(int k=0;k<4;k++){
      float z=wred_sum(lz[k])+__expf(es[k]-m[k]);
      inv[k]=1.f/(z+1e-16f);
    }
  }
  // self-loop
  float acc[4];
  {
    uint2 u=*(const uint2*)(hb+(size_t)n*256+lane4);
    float hv[4]={bflo(u.x),bfhi(u.x),bflo(u.y),bfhi(u.y)};
    #pragma unroll
    for(int k=0;k<4;k++) acc[k]=__expf(es[k]-m[k])*inv[k]*hv[k];
  }
  // chunked accumulate: lane-parallel weights, readlane broadcast, 8 loads in flight
  for(int base=o0;base<o1;base+=64){
    int cnt=min(64,o1-base);
    int j=base+lane;
    int sv=0; float w4[4]={0.f,0.f,0.f,0.f};
    if(j<o1){
      sv=ssrc[j];
      float4 av=*(const float4*)(as_+(size_t)sv*4);
      float a[4]={av.x,av.y,av.z,av.w};
      #pragma unroll
      for(int k=0;k<4;k++) w4[k]=__expf(lrelu(a[k]+ad[k])-m[k])*inv[k];
    }
    int t=0;
    for(; t+8<=cnt; t+=8){
      uint2 u[8];
      #pragma unroll
      for(int i=0;i<8;i++){
        int s=__builtin_amdgcn_readlane(sv,t+i);
        u[i]=*(const uint2*)(hb+(size_t)s*256+lane4);
      }
      #pragma unroll
      for(int i=0;i<8;i++){
        acc[0]+=rlf(w4[0],t+i)*bflo(u[i].x);
        acc[1]+=rlf(w4[1],t+i)*bfhi(u[i].x);
        acc[2]+=rlf(w4[2],t+i)*bflo(u[i].y);
        acc[3]+=rlf(w4[3],t+i)*bfhi(u[i].y);
      }
    }
    for(; t<cnt; t++){
      int s=__builtin_amdgcn_readlane(sv,t);
      uint2 u=*(const uint2*)(hb+(size_t)s*256+lane4);
      acc[0]+=rlf(w4[0],t)*bflo(u.x);
      acc[1]+=rlf(w4[1],t)*bfhi(u.x);
      acc[2]+=rlf(w4[2],t)*bflo(u.y);
      acc[3]+=rlf(w4[3],t)*bfhi(u.y);
    }
  }
  #pragma unroll
  for(int k=0;k<4;k++) acc[k]+=bias[k*64+lane];
  // LayerNorm over 256 + ELU -> bf16 row-major (next GEMM input)
  float tot=wred_sum(acc[0]+acc[1]+acc[2]+acc[3]);
  float mu=tot*(1.f/256.f);
  float vs=0.f;
  #pragma unroll
  for(int k=0;k<4;k++){ float d=acc[k]-mu; vs+=d*d; }
  float var=wred_sum(vs)*(1.f/256.f);
  float r=rsqrtf(var+1e-5f);
  #pragma unroll
  for(int k=0;k<4;k++){
    float v=(acc[k]-mu)*r*g[k*64+lane]+be[k*64+lane];
    float ev= v>0.f? v : expm1f(v);
    outb[(size_t)n*256+k*64+lane]=f2bf(ev);
  }
}

// ---------------- aggregation (heads=1, ch=32, bf16 h) + bias -> d_out ----------------
__global__ __launch_bounds__(256) void agg1_k(const ushort* __restrict__ hb,
    const float* __restrict__ as_,const float* __restrict__ ad_,
    const int* __restrict__ offs,const int* __restrict__ ssrc,
    const float* __restrict__ bias,float* __restrict__ out,int N){
  int lane=threadIdx.x&63, wv=threadIdx.x>>6;
  int n=blockIdx.x*4+wv; if(n>=N) return;
  float ad=ad_[n];
  float es=lrelu(as_[n]+ad);
  int o0=offs[n],o1=offs[n+1];
  float m=es;
  {
    float lm=-1e30f;
    for(int j=o0+lane;j<o1;j+=64) lm=fmaxf(lm,lrelu(as_[ssrc[j]]+ad));
    m=fmaxf(m,wred_max(lm));
  }
  float inv;
  {
    float lz=0.f;
    for(int j=o0+lane;j<o1;j+=64) lz+=__expf(lrelu(as_[ssrc[j]]+ad)-m);
    float z=wred_sum(lz)+__expf(es-m);
    inv=1.f/(z+1e-16f);
  }
  float acc=0.f;
  if(lane<32) acc=__expf(es-m)*inv*__uint_as_float(((unsigned)hb[(size_t)n*32+lane])<<16);
  for(int base=o0;base<o1;base+=64){
    int cnt=min(64,o1-base);
    int j=base+lane;
    int sv=0; float wv1=0.f;
    if(j<o1){
      sv=ssrc[j];
      wv1=__expf(lrelu(as_[sv]+ad)-m)*inv;
    }
    int t=0;
    for(; t+8<=cnt; t+=8){
      float hv[8];
      #pragma unroll
      for(int i=0;i<8;i++){
        int s=__builtin_amdgcn_readlane(sv,t+i);
        hv[i]=(lane<32)?__uint_as_float(((unsigned)hb[(size_t)s*32+lane])<<16):0.f;
      }
      #pragma unroll
      for(int i=0;i<8;i++) acc+=rlf(wv1,t+i)*hv[i];
    }
    for(; t<cnt; t++){
      int s=__builtin_amdgcn_readlane(sv,t);
      if(lane<32) acc+=rlf(wv1,t)*__uint_as_float(((unsigned)hb[(size_t)s*32+lane])<<16);
    }
  }
  if(lane<32) out[(size_t)n*32+lane]=acc+bias[lane];
}

extern "C" void kernel_launch(void* const* d_in,const int* in_sizes,int n_in,
                              void* d_out,int out_size,void* d_ws,size_t ws_size,
                              hipStream_t stream){
  const float* x  =(const float*)d_in[0];
  const int*   ei =(const int*)  d_in[1];
  const float* W1 =(const float*)d_in[2];
  const float* a1s=(const float*)d_in[3];
  const float* a1d=(const float*)d_in[4];
  const float* b1 =(const float*)d_in[5];
  const float* g1 =(const float*)d_in[6];
  const float* be1=(const float*)d_in[7];
  const float* W2 =(const float*)d_in[8];
  const float* a2s=(const float*)d_in[9];
  const float* a2d=(const float*)d_in[10];
  const float* b2 =(const float*)d_in[11];
  const float* g2 =(const float*)d_in[12];
  const float* be2=(const float*)d_in[13];
  const float* W3 =(const float*)d_in[14];
  const float* a3s=(const float*)d_in[15];
  const float* a3d=(const float*)d_in[16];
  const float* b3 =(const float*)d_in[17];
  float* outp=(float*)d_out;
  int N=NN;
  int E=in_sizes[1]/2;
  const int* srcA=ei;
  const int* dstA=ei+E;

  char* w=(char*)d_ws;
  ushort* hb =(ushort*)w; w+=(size_t)N*256*2;   // bf16 permuted h (layers 1-2)
  ushort* h3b=(ushort*)w; w+=(size_t)N*32*2;    // bf16 h (layer 3)
  ushort* obb=(ushort*)w; w+=(size_t)N*256*2;   // bf16 row-major (next GEMM input)
  ushort* xb =(ushort*)w; w+=(size_t)N*128*2;
  ushort* w1t=(ushort*)w; w+=(size_t)256*128*2;
  ushort* w2t=(ushort*)w; w+=(size_t)256*256*2;
  ushort* w3t=(ushort*)w; w+=(size_t)32*256*2;
  float* asb =(float*)w; w+=(size_t)N*4*4;
  float* adb =(float*)w; w+=(size_t)N*4*4;
  int* offs=(int*)w; w+=(size_t)(N+4)*4;
  int* cur =(int*)w; w+=(size_t)N*4;
  int* ssrc=(int*)w; w+=(size_t)E*4;

  // CSR by dst
  hipMemsetAsync(cur,0,(size_t)N*4,stream);
  hist_k<<<(E+255)/256,256,0,stream>>>(dstA,cur,E);
  scan_k<<<1,1024,0,stream>>>(cur,offs,N,E);
  hipMemsetAsync(cur,0,(size_t)N*4,stream);
  scatter_k<<<(E+255)/256,256,0,stream>>>(srcA,dstA,offs,cur,ssrc,E);

  // casts
  castrow_k<<<(N*128+255)/256,256,0,stream>>>(x,xb,N*128);
  casttr_k<<<(128*256+255)/256,256,0,stream>>>(W1,w1t,128,256);
  casttr_k<<<(256*256+255)/256,256,0,stream>>>(W2,w2t,256,256);
  casttr_k<<<(256*32+255)/256,256,0,stream>>>(W3,w3t,256,32);

  int nblkN=(N+3)/4;          // 12500
  int gemmY=(N+127)/128;      // 391

  // layer 1: xb[50000,128] @ W1t[256,128]^T -> bf16 permuted
  gemm_bf16_k<2,2,4,4,1><<<dim3(2,gemmY),256,0,stream>>>(xb,w1t,hb,N,256,128);
  attdot4_k<<<nblkN,256,0,stream>>>(hb,a1s,a1d,asb,adb,N);
  agg4_k<<<nblkN,256,0,stream>>>(hb,asb,adb,offs,ssrc,b1,g1,be1,obb,N);

  // layer 2: obb[50000,256] @ W2t[256,256]^T -> bf16 permuted
  gemm_bf16_k<2,2,4,4,1><<<dim3(2,gemmY),256,0,stream>>>(obb,w2t,hb,N,256,256);
  attdot4_k<<<nblkN,256,0,stream>>>(hb,a2s,a2d,asb,adb,N);
  agg4_k<<<nblkN,256,0,stream>>>(hb,asb,adb,offs,ssrc,b2,g2,be2,obb,N);

  // layer 3: obb[50000,256] @ W3t[32,256]^T -> bf16 row-major
  gemm_bf16_k<4,1,2,2,2><<<dim3(1,gemmY),256,0,stream>>>(obb,w3t,h3b,N,32,256);
  attdot1_k<<<nblkN,256,0,stream>>>(h3b,a3s,a3d,asb,adb,N);
  agg1_k<<<nblkN,256,0,stream>>>(h3b,asb,adb,offs,ssrc,b3,outp,N);
}

// Round 5
// 364.879 us; speedup vs baseline: 2.6836x; 1.3285x over previous
//
#include <hip/hip_runtime.h>
#include <math.h>

#define NN 50000

typedef __attribute__((ext_vector_type(8))) short bf16x8;
typedef __attribute__((ext_vector_type(4))) float f32x4;

__device__ inline float wred_max(float v){
  #pragma unroll
  for(int s=32;s>0;s>>=1) v=fmaxf(v,__shfl_xor(v,s,64));
  return v;
}
__device__ inline float wred_sum(float v){
  #pragma unroll
  for(int s=32;s>0;s>>=1) v+=__shfl_xor(v,s,64);
  return v;
}
__device__ inline float lrelu(float x){ return x>0.f? x : 0.2f*x; }
__device__ inline float rlf(float v,int l){ return __int_as_float(__builtin_amdgcn_readlane(__float_as_int(v),l)); }

__device__ inline ushort f2bf(float f){
  union{float f;unsigned u;} v; v.f=f;
  unsigned u=v.u;
  return (ushort)((u + 0x7fffu + ((u>>16)&1u)) >> 16);
}
__device__ inline float bflo(unsigned u){ return __uint_as_float(u<<16); }
__device__ inline float bfhi(unsigned u){ return __uint_as_float(u&0xffff0000u); }

// ---------------- casts (weights only) ----------------
// W[K,N] f32 -> Wt[N,K] bf16
__global__ void casttr_k(const float* __restrict__ W, ushort* __restrict__ Wt, int K, int N){
  int i=blockIdx.x*blockDim.x+threadIdx.x;
  if(i<K*N){ int k=i/N, n=i%N; Wt[n*K+k]=f2bf(W[i]); }
}

// ---------------- CSR build ----------------
__global__ void hist_k(const int* __restrict__ dstA,int* __restrict__ counts,int E){
  int i=blockIdx.x*blockDim.x+threadIdx.x;
  if(i<E) atomicAdd(&counts[dstA[i]],1);
}

// hierarchical scan: 1) per-block exclusive scan + block sums
__global__ __launch_bounds__(1024) void scan1_k(const int* __restrict__ counts,int* __restrict__ offs,
                                                int* __restrict__ bsum,int N){
  __shared__ int stot[16];
  int t=threadIdx.x; int lane=t&63, wv=t>>6;
  int base=blockIdx.x*1024;
  int orig=(base+t<N)?counts[base+t]:0;
  int v=orig;
  #pragma unroll
  for(int s=1;s<64;s<<=1){ int u=__shfl_up(v,s,64); if(lane>=s) v+=u; }
  if(lane==63) stot[wv]=v;
  __syncthreads();
  if(wv==0){
    int tv=(lane<16)?stot[lane]:0;
    #pragma unroll
    for(int s=1;s<16;s<<=1){ int u=__shfl_up(tv,s,64); if(lane>=s) tv+=u; }
    if(lane<16) stot[lane]=tv;
  }
  __syncthreads();
  int wpref=(wv>0)?stot[wv-1]:0;
  if(base+t<N) offs[base+t]=wpref+v-orig;  // block-local exclusive
  if(t==1023) bsum[blockIdx.x]=stot[15];
}
// 2) scan of block sums (NB<=64) -> exclusive bases
__global__ void scan2_k(int* __restrict__ bsum,int NB){
  int lane=threadIdx.x;
  int v=(lane<NB)?bsum[lane]:0;
  int incl=v;
  #pragma unroll
  for(int s=1;s<64;s<<=1){ int u=__shfl_up(incl,s,64); if(lane>=s) incl+=u; }
  if(lane<NB) bsum[lane]=incl-v;  // exclusive base
}
// 3) add bases
__global__ __launch_bounds__(1024) void scan3_k(int* __restrict__ offs,const int* __restrict__ bsum,int N,int E){
  int i=blockIdx.x*1024+threadIdx.x;
  if(i<N) offs[i]+=bsum[blockIdx.x];
  if(i==N-1) offs[N]=E;
}

__global__ void scatter_k(const int* __restrict__ srcA,const int* __restrict__ dstA,
                          const int* __restrict__ offs,int* cur,int* __restrict__ ssrc,int E){
  int i=blockIdx.x*blockDim.x+threadIdx.x;
  if(i<E){ int d=dstA[i]; int p=offs[d]+atomicAdd(&cur[d],1); ssrc[p]=srcA[i]; }
}

// ---------------- bf16 MFMA GEMM + fused attention dots ----------------
// C = A[M,K] @ Bt[N,K]^T.  BN must equal N (full row per block).
// AF32: A is f32 (convert during staging). 
// DOTM=1: heads=4,N=256, store bf16 head-interleaved perm (chan c -> 4*(c&63)+(c>>6)),
//         write as_[gr*4+h], ad_[gr*4+h].
// DOTM=2: heads=1,N=32, store bf16 row-major, write as_[gr], ad_[gr].
template<int WR,int WC,int MI,int NI,int DOTM,int AF32>
__global__ __launch_bounds__(256) void gemm_bf16_k(const void* __restrict__ Av,
    const ushort* __restrict__ Bt, ushort* __restrict__ C,
    const float* __restrict__ aS, const float* __restrict__ aD,
    float* __restrict__ as_, float* __restrict__ ad_,
    int M, int N, int K){
  constexpr int BM = WR*MI*16;
  constexpr int BN = WC*NI*16;
  constexpr int LDK = 40;
  __shared__ ushort sA[BM*LDK];
  __shared__ ushort sB[BN*LDK];
  int tid=threadIdx.x;
  int lane=tid&63, w=tid>>6;
  int wr=w/WC, wc=w%WC;
  int bm=blockIdx.y*BM;
  f32x4 acc[MI][NI]={};

  for(int k0=0;k0<K;k0+=32){
    if constexpr (AF32){
      const float* A=(const float*)Av;
      #pragma unroll
      for(int i=0;i<(BM*8)/256;i++){
        int c=tid+i*256;
        int r=c>>3, cc=c&7;
        int gr=bm+r;
        float4 v={0.f,0.f,0.f,0.f};
        if(gr<M) v=*(const float4*)(A+(size_t)gr*K+k0+cc*4);
        unsigned long long p=(unsigned long long)f2bf(v.x)
          |((unsigned long long)f2bf(v.y)<<16)
          |((unsigned long long)f2bf(v.z)<<32)
          |((unsigned long long)f2bf(v.w)<<48);
        *(unsigned long long*)(sA+r*LDK+cc*4)=p;
      }
    } else {
      const ushort* A=(const ushort*)Av;
      #pragma unroll
      for(int i=0;i<(BM*4)/256;i++){
        int c=tid+i*256;
        int r=c>>2, cc=c&3;
        int gr=bm+r;
        ulonglong2 v; v.x=0; v.y=0;
        if(gr<M) v=*(const ulonglong2*)(A+(size_t)gr*K+k0+cc*8);
        *(ulonglong2*)(sA+r*LDK+cc*8)=v;
      }
    }
    if constexpr ((BN*4)>=256){
      #pragma unroll
      for(int i=0;i<(BN*4)/256;i++){
        int c=tid+i*256;
        int r=c>>2, cc=c&3;
        ulonglong2 v=*(const ulonglong2*)(Bt+(size_t)r*K+k0+cc*8);
        *(ulonglong2*)(sB+r*LDK+cc*8)=v;
      }
    } else {
      if(tid<BN*4){
        int r=tid>>2, cc=tid&3;
        ulonglong2 v=*(const ulonglong2*)(Bt+(size_t)r*K+k0+cc*8);
        *(ulonglong2*)(sB+r*LDK+cc*8)=v;
      }
    }
    __syncthreads();
    bf16x8 af[MI], bf[NI];
    #pragma unroll
    for(int m=0;m<MI;m++)
      af[m]=*(bf16x8*)(sA+((wr*MI+m)*16+(lane&15))*LDK+(lane>>4)*8);
    #pragma unroll
    for(int n=0;n<NI;n++)
      bf[n]=*(bf16x8*)(sB+((wc*NI+n)*16+(lane&15))*LDK+(lane>>4)*8);
    #pragma unroll
    for(int m=0;m<MI;m++)
      #pragma unroll
      for(int n=0;n<NI;n++)
        acc[m][n]=__builtin_amdgcn_mfma_f32_16x16x32_bf16(af[m],bf[n],acc[m][n],0,0,0);
    __syncthreads();
  }
  int rb=lane>>4, cl=lane&15;
  // per-thread attention-vector slices
  float av[NI], dv[NI];
  #pragma unroll
  for(int n=0;n<NI;n++){
    int gc=(wc*NI+n)*16+cl;
    if constexpr (DOTM!=0){ av[n]=aS[gc]; dv[n]=aD[gc]; }
    else { av[n]=0.f; dv[n]=0.f; }
  }
  #pragma unroll
  for(int m=0;m<MI;m++){
    #pragma unroll
    for(int i=0;i<4;i++){
      int gr=bm+(wr*MI+m)*16+rb*4+i;
      if constexpr (DOTM==1){
        float psA=0.f,psB=0.f,pdA=0.f,pdB=0.f;
        #pragma unroll
        for(int n=0;n<4;n++){ psA+=acc[m][n][i]*av[n]; pdA+=acc[m][n][i]*dv[n]; }
        #pragma unroll
        for(int n=4;n<8;n++){ psB+=acc[m][n][i]*av[n]; pdB+=acc[m][n][i]*dv[n]; }
        #pragma unroll
        for(int msk=1;msk<16;msk<<=1){
          psA+=__shfl_xor(psA,msk,64); psB+=__shfl_xor(psB,msk,64);
          pdA+=__shfl_xor(pdA,msk,64); pdB+=__shfl_xor(pdB,msk,64);
        }
        if(cl==0 && gr<M){
          as_[gr*4+wc*2  ]=psA; as_[gr*4+wc*2+1]=psB;
          ad_[gr*4+wc*2  ]=pdA; ad_[gr*4+wc*2+1]=pdB;
        }
      } else if constexpr (DOTM==2){
        float ps=0.f,pd=0.f;
        #pragma unroll
        for(int n=0;n<NI;n++){ ps+=acc[m][n][i]*av[n]; pd+=acc[m][n][i]*dv[n]; }
        #pragma unroll
        for(int msk=1;msk<16;msk<<=1){
          ps+=__shfl_xor(ps,msk,64); pd+=__shfl_xor(pd,msk,64);
        }
        if(cl==0 && gr<M){ as_[gr]=ps; ad_[gr]=pd; }
      }
      if(gr<M){
        #pragma unroll
        for(int n=0;n<NI;n++){
          int gc=(wc*NI+n)*16+cl;
          int pos = (DOTM==1) ? (4*(gc&63)+(gc>>6)) : gc;
          C[(size_t)gr*N+pos]=f2bf(acc[m][n][i]);
        }
      }
    }
  }
}

// ---------------- aggregation (heads=4, bf16 permuted h) + bias + LN + ELU ----------------
__global__ __launch_bounds__(256) void agg4_k(const ushort* __restrict__ hb,
    const float* __restrict__ as_,const float* __restrict__ ad_,
    const int* __restrict__ offs,const int* __restrict__ ssrc,
    const float* __restrict__ bias,const float* __restrict__ g,const float* __restrict__ be,
    ushort* __restrict__ outb,int N){
  int lane=threadIdx.x&63, wv=threadIdx.x>>6;
  int n=blockIdx.x*4+wv; if(n>=N) return;
  int lane4=lane*4;
  float ad[4], es[4];
  #pragma unroll
  for(int k=0;k<4;k++) ad[k]=ad_[n*4+k];
  #pragma unroll
  for(int k=0;k<4;k++) es[k]=lrelu(as_[n*4+k]+ad[k]);
  int o0=offs[n],o1=offs[n+1];
  int cnt=o1-o0;
  float m[4], inv[4], acc[4];

  if(cnt<=64){
    // ---- fast path: single gather, logits stay in registers ----
    int sv=0;
    float lv[4]={-1e30f,-1e30f,-1e30f,-1e30f};
    if(lane<cnt){
      sv=ssrc[o0+lane];
      float4 avv=*(const float4*)(as_+(size_t)sv*4);
      lv[0]=lrelu(avv.x+ad[0]); lv[1]=lrelu(avv.y+ad[1]);
      lv[2]=lrelu(avv.z+ad[2]); lv[3]=lrelu(avv.w+ad[3]);
    }
    #pragma unroll
    for(int k=0;k<4;k++) m[k]=fmaxf(es[k],wred_max(lv[k]));
    float w4[4];
    #pragma unroll
    for(int k=0;k<4;k++) w4[k]=(lane<cnt)?__expf(lv[k]-m[k]):0.f;
    #pragma unroll
    for(int k=0;k<4;k++){
      float z=wred_sum(w4[k])+__expf(es[k]-m[k]);
      inv[k]=1.f/(z+1e-16f);
    }
    #pragma unroll
    for(int k=0;k<4;k++) w4[k]*=inv[k];
    { // self-loop
      uint2 u=*(const uint2*)(hb+(size_t)n*256+lane4);
      float hv[4]={bflo(u.x),bfhi(u.x),bflo(u.y),bfhi(u.y)};
      #pragma unroll
      for(int k=0;k<4;k++) acc[k]=__expf(es[k]-m[k])*inv[k]*hv[k];
    }
    int t=0;
    for(; t+8<=cnt; t+=8){
      uint2 u[8];
      #pragma unroll
      for(int i=0;i<8;i++){
        int s=__builtin_amdgcn_readlane(sv,t+i);
        u[i]=*(const uint2*)(hb+(size_t)s*256+lane4);
      }
      #pragma unroll
      for(int i=0;i<8;i++){
        acc[0]+=rlf(w4[0],t+i)*bflo(u[i].x);
        acc[1]+=rlf(w4[1],t+i)*bfhi(u[i].x);
        acc[2]+=rlf(w4[2],t+i)*bflo(u[i].y);
        acc[3]+=rlf(w4[3],t+i)*bfhi(u[i].y);
      }
    }
    for(; t<cnt; t++){
      int s=__builtin_amdgcn_readlane(sv,t);
      uint2 u=*(const uint2*)(hb+(size_t)s*256+lane4);
      acc[0]+=rlf(w4[0],t)*bflo(u.x);
      acc[1]+=rlf(w4[1],t)*bfhi(u.x);
      acc[2]+=rlf(w4[2],t)*bflo(u.y);
      acc[3]+=rlf(w4[3],t)*bfhi(u.y);
    }
  } else {
    // ---- slow path (deg>64, rare): 3-sweep recompute ----
    #pragma unroll
    for(int k=0;k<4;k++) m[k]=es[k];
    {
      float lm[4]={-1e30f,-1e30f,-1e30f,-1e30f};
      for(int j=o0+lane;j<o1;j+=64){
        int s=ssrc[j];
        float4 avv=*(const float4*)(as_+(size_t)s*4);
        float a[4]={avv.x,avv.y,avv.z,avv.w};
        #pragma unroll
        for(int k=0;k<4;k++) lm[k]=fmaxf(lm[k],lrelu(a[k]+ad[k]));
      }
      #pragma unroll
      for(int k=0;k<4;k++) m[k]=fmaxf(m[k],wred_max(lm[k]));
    }
    {
      float lz[4]={0.f,0.f,0.f,0.f};
      for(int j=o0+lane;j<o1;j+=64){
        int s=ssrc[j];
        float4 avv=*(const float4*)(as_+(size_t)s*4);
        float a[4]={avv.x,avv.y,avv.z,avv.w};
        #pragma unroll
        for(int k=0;k<4;k++) lz[k]+=__expf(lrelu(a[k]+ad[k])-m[k]);
      }
      #pragma unroll
      for(int k=0;k<4;k++){
        float z=wred_sum(lz[k])+__expf(es[k]-m[k]);
        inv[k]=1.f/(z+1e-16f);
      }
    }
    {
      uint2 u=*(const uint2*)(hb+(size_t)n*256+lane4);
      float hv[4]={bflo(u.x),bfhi(u.x),bflo(u.y),bfhi(u.y)};
      #pragma unroll
      for(int k=0;k<4;k++) acc[k]=__expf(es[k]-m[k])*inv[k]*hv[k];
    }
    for(int base=o0;base<o1;base+=64){
      int c2=min(64,o1-base);
      int j=base+lane;
      int sv=0; float w4[4]={0.f,0.f,0.f,0.f};
      if(j<o1){
        sv=ssrc[j];
        float4 avv=*(const float4*)(as_+(size_t)sv*4);
        float a[4]={avv.x,avv.y,avv.z,avv.w};
        #pragma unroll
        for(int k=0;k<4;k++) w4[k]=__expf(lrelu(a[k]+ad[k])-m[k])*inv[k];
      }
      for(int t=0;t<c2;t++){
        int s=__builtin_amdgcn_readlane(sv,t);
        uint2 u=*(const uint2*)(hb+(size_t)s*256+lane4);
        acc[0]+=rlf(w4[0],t)*bflo(u.x);
        acc[1]+=rlf(w4[1],t)*bfhi(u.x);
        acc[2]+=rlf(w4[2],t)*bflo(u.y);
        acc[3]+=rlf(w4[3],t)*bfhi(u.y);
      }
    }
  }
  #pragma unroll
  for(int k=0;k<4;k++) acc[k]+=bias[k*64+lane];
  // LayerNorm over 256 + ELU -> bf16 row-major (next GEMM input)
  float tot=wred_sum(acc[0]+acc[1]+acc[2]+acc[3]);
  float mu=tot*(1.f/256.f);
  float vs=0.f;
  #pragma unroll
  for(int k=0;k<4;k++){ float d=acc[k]-mu; vs+=d*d; }
  float var=wred_sum(vs)*(1.f/256.f);
  float r=rsqrtf(var+1e-5f);
  #pragma unroll
  for(int k=0;k<4;k++){
    float v=(acc[k]-mu)*r*g[k*64+lane]+be[k*64+lane];
    float ev= v>0.f? v : expm1f(v);
    outb[(size_t)n*256+k*64+lane]=f2bf(ev);
  }
}

// ---------------- aggregation (heads=1, ch=32, bf16 h) + bias -> d_out ----------------
__global__ __launch_bounds__(256) void agg1_k(const ushort* __restrict__ hb,
    const float* __restrict__ as_,const float* __restrict__ ad_,
    const int* __restrict__ offs,const int* __restrict__ ssrc,
    const float* __restrict__ bias,float* __restrict__ out,int N){
  int lane=threadIdx.x&63, wv=threadIdx.x>>6;
  int n=blockIdx.x*4+wv; if(n>=N) return;
  float ad=ad_[n];
  float es=lrelu(as_[n]+ad);
  int o0=offs[n],o1=offs[n+1];
  int cnt=o1-o0;
  float m, inv, acc=0.f;

  if(cnt<=64){
    int sv=0; float lv=-1e30f;
    if(lane<cnt){ sv=ssrc[o0+lane]; lv=lrelu(as_[sv]+ad); }
    m=fmaxf(es,wred_max(lv));
    float w1=(lane<cnt)?__expf(lv-m):0.f;
    float z=wred_sum(w1)+__expf(es-m);
    inv=1.f/(z+1e-16f);
    w1*=inv;
    if(lane<32) acc=__expf(es-m)*inv*__uint_as_float(((unsigned)hb[(size_t)n*32+lane])<<16);
    int t=0;
    for(; t+8<=cnt; t+=8){
      float hv[8];
      #pragma unroll
      for(int i=0;i<8;i++){
        int s=__builtin_amdgcn_readlane(sv,t+i);
        hv[i]=(lane<32)?__uint_as_float(((unsigned)hb[(size_t)s*32+lane])<<16):0.f;
      }
      #pragma unroll
      for(int i=0;i<8;i++) acc+=rlf(w1,t+i)*hv[i];
    }
    for(; t<cnt; t++){
      int s=__builtin_amdgcn_readlane(sv,t);
      if(lane<32) acc+=rlf(w1,t)*__uint_as_float(((unsigned)hb[(size_t)s*32+lane])<<16);
    }
  } else {
    m=es;
    {
      float lm=-1e30f;
      for(int j=o0+lane;j<o1;j+=64) lm=fmaxf(lm,lrelu(as_[ssrc[j]]+ad));
      m=fmaxf(m,wred_max(lm));
    }
    {
      float lz=0.f;
      for(int j=o0+lane;j<o1;j+=64) lz+=__expf(lrelu(as_[ssrc[j]]+ad)-m);
      float z=wred_sum(lz)+__expf(es-m);
      inv=1.f/(z+1e-16f);
    }
    if(lane<32) acc=__expf(es-m)*inv*__uint_as_float(((unsigned)hb[(size_t)n*32+lane])<<16);
    for(int base=o0;base<o1;base+=64){
      int c2=min(64,o1-base);
      int j=base+lane;
      int sv=0; float w1=0.f;
      if(j<o1){ sv=ssrc[j]; w1=__expf(lrelu(as_[sv]+ad)-m)*inv; }
      for(int t=0;t<c2;t++){
        int s=__builtin_amdgcn_readlane(sv,t);
        if(lane<32) acc+=rlf(w1,t)*__uint_as_float(((unsigned)hb[(size_t)s*32+lane])<<16);
      }
    }
  }
  if(lane<32) out[(size_t)n*32+lane]=acc+bias[lane];
}

extern "C" void kernel_launch(void* const* d_in,const int* in_sizes,int n_in,
                              void* d_out,int out_size,void* d_ws,size_t ws_size,
                              hipStream_t stream){
  const float* x  =(const float*)d_in[0];
  const int*   ei =(const int*)  d_in[1];
  const float* W1 =(const float*)d_in[2];
  const float* a1s=(const float*)d_in[3];
  const float* a1d=(const float*)d_in[4];
  const float* b1 =(const float*)d_in[5];
  const float* g1 =(const float*)d_in[6];
  const float* be1=(const float*)d_in[7];
  const float* W2 =(const float*)d_in[8];
  const float* a2s=(const float*)d_in[9];
  const float* a2d=(const float*)d_in[10];
  const float* b2 =(const float*)d_in[11];
  const float* g2 =(const float*)d_in[12];
  const float* be2=(const float*)d_in[13];
  const float* W3 =(const float*)d_in[14];
  const float* a3s=(const float*)d_in[15];
  const float* a3d=(const float*)d_in[16];
  const float* b3 =(const float*)d_in[17];
  float* outp=(float*)d_out;
  int N=NN;
  int E=in_sizes[1]/2;
  const int* srcA=ei;
  const int* dstA=ei+E;

  char* w=(char*)d_ws;
  ushort* hb =(ushort*)w; w+=(size_t)N*256*2;   // bf16 permuted h (layers 1-2)
  ushort* h3b=(ushort*)w; w+=(size_t)N*32*2;    // bf16 h (layer 3)
  ushort* obb=(ushort*)w; w+=(size_t)N*256*2;   // bf16 row-major (next GEMM input)
  ushort* w1t=(ushort*)w; w+=(size_t)256*128*2;
  ushort* w2t=(ushort*)w; w+=(size_t)256*256*2;
  ushort* w3t=(ushort*)w; w+=(size_t)32*256*2;
  float* asb =(float*)w; w+=(size_t)N*4*4;
  float* adb =(float*)w; w+=(size_t)N*4*4;
  int* offs=(int*)w; w+=(size_t)(N+4)*4;
  int* cur =(int*)w; w+=(size_t)N*4;
  int* ssrc=(int*)w; w+=(size_t)E*4;
  int* bsum=(int*)w; w+=(size_t)64*4;

  int NB=(N+1023)/1024;  // 49

  // CSR by dst
  hipMemsetAsync(cur,0,(size_t)N*4,stream);
  hist_k<<<(E+255)/256,256,0,stream>>>(dstA,cur,E);
  scan1_k<<<NB,1024,0,stream>>>(cur,offs,bsum,N);
  scan2_k<<<1,64,0,stream>>>(bsum,NB);
  scan3_k<<<NB,1024,0,stream>>>(offs,bsum,N,E);
  hipMemsetAsync(cur,0,(size_t)N*4,stream);
  scatter_k<<<(E+255)/256,256,0,stream>>>(srcA,dstA,offs,cur,ssrc,E);

  // weight casts
  casttr_k<<<(128*256+255)/256,256,0,stream>>>(W1,w1t,128,256);
  casttr_k<<<(256*256+255)/256,256,0,stream>>>(W2,w2t,256,256);
  casttr_k<<<(256*32+255)/256,256,0,stream>>>(W3,w3t,256,32);

  int nblkN=(N+3)/4;          // 12500
  int gY64=(N+63)/64;         // 782
  int gY128=(N+127)/128;      // 391

  // layer 1: x[50000,128](f32) @ W1t[256,128]^T -> bf16 permuted + dots
  gemm_bf16_k<2,2,2,8,1,1><<<dim3(1,gY64),256,0,stream>>>(x,w1t,hb,a1s,a1d,asb,adb,N,256,128);
  agg4_k<<<nblkN,256,0,stream>>>(hb,asb,adb,offs,ssrc,b1,g1,be1,obb,N);

  // layer 2: obb[50000,256] @ W2t[256,256]^T -> bf16 permuted + dots
  gemm_bf16_k<2,2,2,8,1,0><<<dim3(1,gY64),256,0,stream>>>(obb,w2t,hb,a2s,a2d,asb,adb,N,256,256);
  agg4_k<<<nblkN,256,0,stream>>>(hb,asb,adb,offs,ssrc,b2,g2,be2,obb,N);

  // layer 3: obb[50000,256] @ W3t[32,256]^T -> bf16 row-major + dots (heads=1)
  gemm_bf16_k<4,1,2,2,2,0><<<dim3(1,gY128),256,0,stream>>>(obb,w3t,h3b,a3s,a3d,asb,adb,N,32,256);
  agg1_k<<<nblkN,256,0,stream>>>(h3b,asb,adb,offs,ssrc,b3,outp,N);
}